// Round 4
// baseline (329.439 us; speedup 1.0000x reference)
//
#include <hip/hip_runtime.h>
#include <stdint.h>

typedef __attribute__((ext_vector_type(8))) short  short8;   // 8 bf16 = 4 VGPR MFMA frag
typedef __attribute__((ext_vector_type(4))) float  f32x4;    // MFMA accumulator
typedef __attribute__((ext_vector_type(4))) unsigned short us4;

static __device__ __forceinline__ unsigned short f2bf(float x) {
  unsigned u = __builtin_bit_cast(unsigned, x);
  u += 0x7FFFu + ((u >> 16) & 1u);          // round-to-nearest-even
  return (unsigned short)(u >> 16);
}

static __device__ __forceinline__ unsigned cvt_pk_bf16(float lo, float hi) {
  unsigned r;
  asm("v_cvt_pk_bf16_f32 %0, %1, %2" : "=v"(r) : "v"(lo), "v"(hi));
  return r;
}

// max with DPP-shuffled self (reduction over 16-lane row)
template <int CTRL>
static __device__ __forceinline__ float maxdpp(float v) {
  int o = __builtin_amdgcn_update_dpp(0, __builtin_bit_cast(int, v), CTRL, 0xf, 0xf, false);
  return fmaxf(v, __builtin_bit_cast(float, o));
}
static __device__ __forceinline__ float rowmax16(float v) {
  v = maxdpp<0xB1>(v);    // quad_perm [1,0,3,2]  (xor 1)
  v = maxdpp<0x4E>(v);    // quad_perm [2,3,0,1]  (xor 2)
  v = maxdpp<0x141>(v);   // row_half_mirror      (xor 4 after quads uniform)
  v = maxdpp<0x140>(v);   // row_mirror           (xor 8 after halves uniform)
  return v;
}

// ---------------------------------------------------------------- fp32 -> bf16
__global__ __launch_bounds__(256) void cvt_kernel(const float* __restrict__ in,
                                                  unsigned short* __restrict__ out,
                                                  int n4) {
  int i = blockIdx.x * blockDim.x + threadIdx.x;
  int stride = gridDim.x * blockDim.x;
  for (; i < n4; i += stride) {
    f32x4 v = *((const f32x4*)in + i);
    us4 o = { f2bf(v[0]), f2bf(v[1]), f2bf(v[2]), f2bf(v[3]) };
    *((us4*)out + i) = o;
  }
}

// --------------------------------------------- pmask -> f32 bias + 64-key tile flags
__global__ __launch_bounds__(64) void bias_kernel(const int* __restrict__ pm,
                                                  float* __restrict__ bias,
                                                  int* __restrict__ flags) {
  int j = blockIdx.x;                       // (b, kt) pair, 128 total
  int i = j * 64 + threadIdx.x;
  int z = pm[i];
  bias[i] = (z == 0) ? -1.0e9f : 0.0f;
  unsigned long long m = __ballot(z == 0);
  if (threadIdx.x == 0) flags[j] = (m != 0ull) ? 1 : 0;
}

// ------------------------------------------------------- async global->LDS 16B
static __device__ __forceinline__ void g2l16(const void* g, void* l) {
  __builtin_amdgcn_global_load_lds(
      (const __attribute__((address_space(1))) void*)g,
      (__attribute__((address_space(3))) void*)l, 16, 0, 0);
}

// ---------------------------------------------------------------- NT GEMM
// C[m][n] = sum_k A[m][k] * W[n][k].  A: MxK bf16, W: NxK bf16.
// BM=BN=128, BK=32, 256 threads = 4 waves (2x2), 64x64 per wave.
// MODE 0: bf16 out (scaled), row-major. MODE 1: bf16 out transposed for V.
// MODE 2: f32 out row-major.
template <int MODE>
__global__ __launch_bounds__(256) void gemm_nt(const unsigned short* __restrict__ A,
                                               const unsigned short* __restrict__ W,
                                               void* __restrict__ outp,
                                               int M, int N, int K, float scale) {
  __shared__ unsigned short Alds[128 * 32];
  __shared__ unsigned short Blds[128 * 32];
  const int tid  = threadIdx.x;
  const int lane = tid & 63;
  const int w    = tid >> 6;
  const int g    = lane >> 4;
  const int li   = lane & 15;
  const int m0 = blockIdx.y * 128;
  const int n0 = blockIdx.x * 128;
  const int wm = (w >> 1) * 64;
  const int wn = (w & 1) * 64;

  int aoff[4], boff[4];
#pragma unroll
  for (int mi = 0; mi < 4; ++mi) {
    int row = wm + mi * 16 + li;
    aoff[mi] = row * 32 + (g ^ ((row >> 1) & 3)) * 8;
  }
#pragma unroll
  for (int ni = 0; ni < 4; ++ni) {
    int col = wn + ni * 16 + li;
    boff[ni] = col * 32 + (g ^ ((col >> 1) & 3)) * 8;
  }

  const int s1 = tid, s2 = 256 + tid;
  const int r1 = s1 >> 2, gc1 = (s1 & 3) ^ ((r1 >> 1) & 3);
  const int r2 = s2 >> 2, gc2 = (s2 & 3) ^ ((r2 >> 1) & 3);
  const unsigned short* gA1 = A + (size_t)(m0 + r1) * K + gc1 * 8;
  const unsigned short* gA2 = A + (size_t)(m0 + r2) * K + gc2 * 8;
  const unsigned short* gB1 = W + (size_t)(n0 + r1) * K + gc1 * 8;
  const unsigned short* gB2 = W + (size_t)(n0 + r2) * K + gc2 * 8;
  unsigned short* lA1 = &Alds[w * 512];
  unsigned short* lA2 = &Alds[2048 + w * 512];
  unsigned short* lB1 = &Blds[w * 512];
  unsigned short* lB2 = &Blds[2048 + w * 512];

  f32x4 acc[4][4] = {};

  const int nkt = K >> 5;
#pragma unroll 1
  for (int kt = 0; kt < nkt; ++kt) {
    g2l16(gA1, lA1); g2l16(gA2, lA2);
    g2l16(gB1, lB1); g2l16(gB2, lB2);
    gA1 += 32; gA2 += 32; gB1 += 32; gB2 += 32;
    asm volatile("s_waitcnt vmcnt(0)" ::: "memory");
    __syncthreads();
    short8 af[4], bf[4];
#pragma unroll
    for (int mi = 0; mi < 4; ++mi) af[mi] = *(const short8*)&Alds[aoff[mi]];
#pragma unroll
    for (int ni = 0; ni < 4; ++ni) bf[ni] = *(const short8*)&Blds[boff[ni]];
#pragma unroll
    for (int mi = 0; mi < 4; ++mi)
#pragma unroll
      for (int ni = 0; ni < 4; ++ni)
        acc[mi][ni] = __builtin_amdgcn_mfma_f32_16x16x32_bf16(af[mi], bf[ni], acc[mi][ni], 0, 0, 0);
    __syncthreads();
  }

  if (MODE == 0) {
    unsigned short* C = (unsigned short*)outp;
#pragma unroll
    for (int mi = 0; mi < 4; ++mi) {
      int mb = m0 + wm + mi * 16 + g * 4;
#pragma unroll
      for (int ni = 0; ni < 4; ++ni) {
        int n = n0 + wn + ni * 16 + li;
#pragma unroll
        for (int r = 0; r < 4; ++r)
          C[(size_t)(mb + r) * N + n] = f2bf(acc[mi][ni][r] * scale);
      }
    }
  } else if (MODE == 1) {
    unsigned short* C = (unsigned short*)outp;   // (B*1024) x 2048
#pragma unroll
    for (int mi = 0; mi < 4; ++mi) {
      int mb = m0 + wm + mi * 16 + g * 4;
      int bb = mb >> 11, s = mb & 2047;
#pragma unroll
      for (int ni = 0; ni < 4; ++ni) {
        int n = n0 + wn + ni * 16 + li;
        us4 pk = { f2bf(acc[mi][ni][0]), f2bf(acc[mi][ni][1]),
                   f2bf(acc[mi][ni][2]), f2bf(acc[mi][ni][3]) };
        *(us4*)&C[(size_t)(bb * 1024 + n) * 2048 + s] = pk;
      }
    }
  } else {
    float* C = (float*)outp;
#pragma unroll
    for (int mi = 0; mi < 4; ++mi) {
      int mb = m0 + wm + mi * 16 + g * 4;
#pragma unroll
      for (int ni = 0; ni < 4; ++ni) {
        int n = n0 + wn + ni * 16 + li;
#pragma unroll
        for (int r = 0; r < 4; ++r)
          C[(size_t)(mb + r) * N + n] = acc[mi][ni][r];
      }
    }
  }
}

// ---------------------------------------------------------------- attention v4
// Block = 512 threads (8 waves), one 128-row q-tile of one (b,h). Wave w owns
// 16 q rows. Q pre-scaled by 0.125*log2(e) (folded into Q projection).
// XCD-balanced tile map: XCD k (= blockIdx.x % 8 since gridDim.x=16) gets
// tiles {15-k, k} -> exactly 34 iterations per XCD pair, uniform across XCDs.
__global__ __launch_bounds__(512, 6) void attn_kernel(const unsigned short* __restrict__ Qp,
                                                      const unsigned short* __restrict__ Kp,
                                                      const unsigned short* __restrict__ Vt,
                                                      const float* __restrict__ bias,
                                                      const int* __restrict__ flags,
                                                      unsigned short* __restrict__ att) {
  __shared__ unsigned short Klds[2][64 * 64];
  __shared__ unsigned short Vlds[2][64 * 64];
  __shared__ unsigned short Plds[8][16 * 68];

  const int tid = threadIdx.x, lane = tid & 63, w = tid >> 6;
  const int g = lane >> 4, li = lane & 15;
  const int bh = blockIdx.y, b = bh >> 4, h = bh & 15;
  const int x = blockIdx.x;
  const int t = (x < 8) ? (15 - x) : (x - 8);   // XCD-balanced, long-first
  const int nkt = 2 * t + 2;
  const int qw = t * 128 + w * 16;
  const int ktd = (qw + 15) >> 6;           // diagonal iteration for this wave

  const int srow = tid >> 3, swc = (tid & 7) ^ (srow & 7);
  const unsigned short* Ksrc = Kp + (size_t)(b * 2048 + srow) * 1024 + h * 64 + swc * 8;
  const unsigned short* Vsrc = Vt + (size_t)(b * 1024 + h * 64 + srow) * 2048 + swc * 8;

  int foff[2][4];
#pragma unroll
  for (int ks = 0; ks < 2; ++ks)
#pragma unroll
    for (int i = 0; i < 4; ++i)
      foff[ks][i] = (i * 16 + li) * 64 + (((ks * 4 + g) ^ (li & 7)) * 8);

  unsigned short* Pl = &Plds[w][0];
  const float* bbase = bias + b * 2048 + li;
  const int*   fbase = flags + b * 32;

  short8 ones;
#pragma unroll
  for (int j = 0; j < 8; ++j) ones[j] = (short)0x3F80;  // bf16 1.0

  short8 qfr[2];
#pragma unroll
  for (int ks = 0; ks < 2; ++ks)
    qfr[ks] = *(const short8*)&Qp[((size_t)(b * 2048 + qw + li)) * 1024 +
                                  h * 64 + ks * 32 + g * 8];

  f32x4 acco[4] = {};
  f32x4 lacc = {};
  float mrow[4] = {-3.0e38f, -3.0e38f, -3.0e38f, -3.0e38f};
  const f32x4 Z = {0.f, 0.f, 0.f, 0.f};

  g2l16(Ksrc, &Klds[0][w * 512]);
  g2l16(Vsrc, &Vlds[0][w * 512]);
  const unsigned short* Ksrcn = Ksrc + 65536;
  const unsigned short* Vsrcn = Vsrc + 64;

  int buf = 0;
#pragma unroll 1
  for (int it = 0; it < nkt; ++it) {
    if (it + 1 < nkt) {
      g2l16(Ksrcn, &Klds[buf ^ 1][w * 512]);
      g2l16(Vsrcn, &Vlds[buf ^ 1][w * 512]);
      Ksrcn += 65536; Vsrcn += 64;
      asm volatile("s_waitcnt vmcnt(2)" ::: "memory");
    } else {
      asm volatile("s_waitcnt vmcnt(0)" ::: "memory");
    }
    __builtin_amdgcn_s_barrier();

    if (it <= ktd) {
      // ---- QK^T (Q pre-scaled; scores directly in log2 domain)
      f32x4 s[4];
#pragma unroll
      for (int ni = 0; ni < 4; ++ni) {
        short8 kf = *(const short8*)&Klds[buf][foff[0][ni]];
        s[ni] = __builtin_amdgcn_mfma_f32_16x16x32_bf16(qfr[0], kf, Z, 0, 0, 0);
      }
#pragma unroll
      for (int ni = 0; ni < 4; ++ni) {
        short8 kf = *(const short8*)&Klds[buf][foff[1][ni]];
        s[ni] = __builtin_amdgcn_mfma_f32_16x16x32_bf16(qfr[1], kf, s[ni], 0, 0, 0);
      }
      // ---- padding bias (skipped when this 64-key tile has no padding)
      if (fbase[it]) {
#pragma unroll
        for (int ni = 0; ni < 4; ++ni) {
          float bv = bbase[it * 64 + ni * 16];
#pragma unroll
          for (int r = 0; r < 4; ++r) s[ni][r] += bv;
        }
      }
      // ---- causal mask (only on the diagonal iteration)
      if (it == ktd) {
        const int q0 = qw + g * 4;
#pragma unroll
        for (int ni = 0; ni < 4; ++ni) {
          const int key = it * 64 + ni * 16 + li;
#pragma unroll
          for (int r = 0; r < 4; ++r)
            if (key > q0 + r) s[ni][r] = -1.0e9f;
        }
      }
      // ---- tile max per row (in-lane + DPP over 16 key-lanes)
      float tm[4];
#pragma unroll
      for (int r = 0; r < 4; ++r)
        tm[r] = rowmax16(fmaxf(fmaxf(s[0][r], s[1][r]), fmaxf(s[2][r], s[3][r])));
      // ---- defer-max: rescale only when max grew by > 8 (log2 units)
      int need = 0;
#pragma unroll
      for (int r = 0; r < 4; ++r) need |= (tm[r] > mrow[r] + 8.0f) ? 1 : 0;
      if (__any(need)) {
#pragma unroll
        for (int r = 0; r < 4; ++r) {
          const float mn = fmaxf(mrow[r], tm[r]);
          const float al = exp2f(mrow[r] - mn);
          mrow[r] = mn;
          lacc[r] *= al;
#pragma unroll
          for (int df = 0; df < 4; ++df) acco[df][r] *= al;
        }
      }
      // ---- p = exp2(s - m) -> bf16 (cvt_pk) -> LDS (stride 68)
#pragma unroll
      for (int ni = 0; ni < 4; ++ni) {
#pragma unroll
        for (int h2 = 0; h2 < 2; ++h2) {
          float lo = exp2f(s[ni][2 * h2]     - mrow[2 * h2]);
          float hi = exp2f(s[ni][2 * h2 + 1] - mrow[2 * h2 + 1]);
          unsigned pk = cvt_pk_bf16(lo, hi);
          Pl[(g * 4 + 2 * h2)     * 68 + ni * 16 + li] = (unsigned short)pk;
          Pl[(g * 4 + 2 * h2 + 1) * 68 + ni * 16 + li] = (unsigned short)(pk >> 16);
        }
      }
      // ---- PV (+ ones column for row-sum l)
#pragma unroll
      for (int ks = 0; ks < 2; ++ks) {
        const short8 pa = *(const short8*)&Pl[li * 68 + ks * 32 + g * 8];
        short8 vf[4];
#pragma unroll
        for (int df = 0; df < 4; ++df) vf[df] = *(const short8*)&Vlds[buf][foff[ks][df]];
#pragma unroll
        for (int df = 0; df < 4; ++df)
          acco[df] = __builtin_amdgcn_mfma_f32_16x16x32_bf16(pa, vf[df], acco[df], 0, 0, 0);
        lacc = __builtin_amdgcn_mfma_f32_16x16x32_bf16(pa, ones, lacc, 0, 0, 0);
      }
    }
    __builtin_amdgcn_s_barrier();
    buf ^= 1;
  }

  // ---- epilogue
  float inv[4];
#pragma unroll
  for (int r = 0; r < 4; ++r) inv[r] = 1.0f / lacc[r];
  const int qb0 = qw + g * 4;
#pragma unroll
  for (int df = 0; df < 4; ++df) {
    const int d = h * 64 + df * 16 + li;
#pragma unroll
    for (int r = 0; r < 4; ++r)
      att[(size_t)(b * 2048 + qb0 + r) * 1024 + d] = f2bf(acco[df][r] * inv[r]);
  }
}

// ---------------------------------------------------------------- launch
extern "C" void kernel_launch(void* const* d_in, const int* in_sizes, int n_in,
                              void* d_out, int out_size, void* d_ws, size_t ws_size,
                              hipStream_t stream) {
  const float* q_raw  = (const float*)d_in[0];
  const float* kv_raw = (const float*)d_in[1];
  const int*   pmask  = (const int*)d_in[2];
  const float* Wq = (const float*)d_in[3];
  const float* Wk = (const float*)d_in[4];
  const float* Wv = (const float*)d_in[5];
  const float* Wo = (const float*)d_in[6];
  float* out = (float*)d_out;

  const size_t NEL = 8388608;   // B*S*D
  const size_t WEL = 1048576;   // D*D
  unsigned short* ws   = (unsigned short*)d_ws;
  unsigned short* qbf  = ws;              // reused as att after projections
  unsigned short* kvbf = qbf + NEL;
  unsigned short* wbf  = kvbf + NEL;      // Wq,Wk,Wv,Wo bf16 back-to-back
  unsigned short* Qp   = wbf + 4 * WEL;
  unsigned short* Kp   = Qp + NEL;
  unsigned short* Vtp  = Kp + NEL;        // (B,H,DH,S) transposed V
  float*          bias = (float*)(Vtp + NEL);
  int*            flags = (int*)(bias + 8192);
  unsigned short* att  = qbf;             // alias (qbf dead after projections)

  const float sc = 0.125f * 1.44269504088896340736f;  // 1/sqrt(DH) * log2(e)

  cvt_kernel<<<2048, 256, 0, stream>>>(q_raw,  qbf,  (int)(NEL / 4));
  cvt_kernel<<<2048, 256, 0, stream>>>(kv_raw, kvbf, (int)(NEL / 4));
  cvt_kernel<<<256, 256, 0, stream>>>(Wq, wbf,           (int)(WEL / 4));
  cvt_kernel<<<256, 256, 0, stream>>>(Wk, wbf + WEL,     (int)(WEL / 4));
  cvt_kernel<<<256, 256, 0, stream>>>(Wv, wbf + 2 * WEL, (int)(WEL / 4));
  cvt_kernel<<<256, 256, 0, stream>>>(Wo, wbf + 3 * WEL, (int)(WEL / 4));
  bias_kernel<<<128, 64, 0, stream>>>(pmask, bias, flags);

  dim3 gg(8, 64);  // N/128, M/128
  gemm_nt<0><<<gg, 256, 0, stream>>>(qbf,  wbf,           (void*)Qp,  8192, 1024, 1024, sc);
  gemm_nt<0><<<gg, 256, 0, stream>>>(kvbf, wbf + WEL,     (void*)Kp,  8192, 1024, 1024, 1.0f);
  gemm_nt<1><<<gg, 256, 0, stream>>>(kvbf, wbf + 2 * WEL, (void*)Vtp, 8192, 1024, 1024, 1.0f);

  attn_kernel<<<dim3(16, 64), 512, 0, stream>>>(Qp, Kp, Vtp, bias, flags, att);

  gemm_nt<2><<<gg, 256, 0, stream>>>(att, wbf + 3 * WEL, (void*)out, 8192, 1024, 1024, 1.0f);
}

// Round 5
// 246.540 us; speedup vs baseline: 1.3363x; 1.3363x over previous
//
#include <hip/hip_runtime.h>
#include <stdint.h>

typedef __attribute__((ext_vector_type(8))) short  short8;   // 8 bf16 = 4 VGPR MFMA frag
typedef __attribute__((ext_vector_type(4))) float  f32x4;    // MFMA accumulator
typedef __attribute__((ext_vector_type(4))) unsigned short us4;

static __device__ __forceinline__ unsigned short f2bf(float x) {
  unsigned u = __builtin_bit_cast(unsigned, x);
  u += 0x7FFFu + ((u >> 16) & 1u);          // round-to-nearest-even
  return (unsigned short)(u >> 16);
}

static __device__ __forceinline__ unsigned cvt_pk_bf16(float lo, float hi) {
  unsigned r;
  asm("v_cvt_pk_bf16_f32 %0, %1, %2" : "=v"(r) : "v"(lo), "v"(hi));
  return r;
}

// max with DPP-shuffled self (reduction over 16-lane row)
template <int CTRL>
static __device__ __forceinline__ float maxdpp(float v) {
  int o = __builtin_amdgcn_update_dpp(0, __builtin_bit_cast(int, v), CTRL, 0xf, 0xf, false);
  return fmaxf(v, __builtin_bit_cast(float, o));
}
static __device__ __forceinline__ float rowmax16(float v) {
  v = maxdpp<0xB1>(v);    // quad_perm xor 1
  v = maxdpp<0x4E>(v);    // quad_perm xor 2
  v = maxdpp<0x141>(v);   // row_half_mirror
  v = maxdpp<0x140>(v);   // row_mirror
  return v;
}

// ---------------------------------------------------------------- fp32 -> bf16
__global__ __launch_bounds__(256) void cvt_kernel(const float* __restrict__ in,
                                                  unsigned short* __restrict__ out,
                                                  int n4) {
  int i = blockIdx.x * blockDim.x + threadIdx.x;
  int stride = gridDim.x * blockDim.x;
  for (; i < n4; i += stride) {
    f32x4 v = *((const f32x4*)in + i);
    us4 o = { f2bf(v[0]), f2bf(v[1]), f2bf(v[2]), f2bf(v[3]) };
    *((us4*)out + i) = o;
  }
}

// --------------------------------------------- pmask -> f32 bias + 64-key tile flags
__global__ __launch_bounds__(64) void bias_kernel(const int* __restrict__ pm,
                                                  float* __restrict__ bias,
                                                  int* __restrict__ flags) {
  int j = blockIdx.x;                       // (b, kt) pair, 128 total
  int i = j * 64 + threadIdx.x;
  int z = pm[i];
  bias[i] = (z == 0) ? -1.0e9f : 0.0f;
  unsigned long long m = __ballot(z == 0);
  if (threadIdx.x == 0) flags[j] = (m != 0ull) ? 1 : 0;
}

// ------------------------------------------------------- async global->LDS 16B
static __device__ __forceinline__ void g2l16(const void* g, void* l) {
  __builtin_amdgcn_global_load_lds(
      (const __attribute__((address_space(1))) void*)g,
      (__attribute__((address_space(3))) void*)l, 16, 0, 0);
}

// ---------------------------------------------------------------- NT GEMM
template <int MODE>
__global__ __launch_bounds__(256) void gemm_nt(const unsigned short* __restrict__ A,
                                               const unsigned short* __restrict__ W,
                                               void* __restrict__ outp,
                                               int M, int N, int K, float scale) {
  __shared__ unsigned short Alds[128 * 32];
  __shared__ unsigned short Blds[128 * 32];
  const int tid  = threadIdx.x;
  const int lane = tid & 63;
  const int w    = tid >> 6;
  const int g    = lane >> 4;
  const int li   = lane & 15;
  const int m0 = blockIdx.y * 128;
  const int n0 = blockIdx.x * 128;
  const int wm = (w >> 1) * 64;
  const int wn = (w & 1) * 64;

  int aoff[4], boff[4];
#pragma unroll
  for (int mi = 0; mi < 4; ++mi) {
    int row = wm + mi * 16 + li;
    aoff[mi] = row * 32 + (g ^ ((row >> 1) & 3)) * 8;
  }
#pragma unroll
  for (int ni = 0; ni < 4; ++ni) {
    int col = wn + ni * 16 + li;
    boff[ni] = col * 32 + (g ^ ((col >> 1) & 3)) * 8;
  }

  const int s1 = tid, s2 = 256 + tid;
  const int r1 = s1 >> 2, gc1 = (s1 & 3) ^ ((r1 >> 1) & 3);
  const int r2 = s2 >> 2, gc2 = (s2 & 3) ^ ((r2 >> 1) & 3);
  const unsigned short* gA1 = A + (size_t)(m0 + r1) * K + gc1 * 8;
  const unsigned short* gA2 = A + (size_t)(m0 + r2) * K + gc2 * 8;
  const unsigned short* gB1 = W + (size_t)(n0 + r1) * K + gc1 * 8;
  const unsigned short* gB2 = W + (size_t)(n0 + r2) * K + gc2 * 8;
  unsigned short* lA1 = &Alds[w * 512];
  unsigned short* lA2 = &Alds[2048 + w * 512];
  unsigned short* lB1 = &Blds[w * 512];
  unsigned short* lB2 = &Blds[2048 + w * 512];

  f32x4 acc[4][4] = {};

  const int nkt = K >> 5;
#pragma unroll 1
  for (int kt = 0; kt < nkt; ++kt) {
    g2l16(gA1, lA1); g2l16(gA2, lA2);
    g2l16(gB1, lB1); g2l16(gB2, lB2);
    gA1 += 32; gA2 += 32; gB1 += 32; gB2 += 32;
    asm volatile("s_waitcnt vmcnt(0)" ::: "memory");
    __syncthreads();
    short8 af[4], bf[4];
#pragma unroll
    for (int mi = 0; mi < 4; ++mi) af[mi] = *(const short8*)&Alds[aoff[mi]];
#pragma unroll
    for (int ni = 0; ni < 4; ++ni) bf[ni] = *(const short8*)&Blds[boff[ni]];
#pragma unroll
    for (int mi = 0; mi < 4; ++mi)
#pragma unroll
      for (int ni = 0; ni < 4; ++ni)
        acc[mi][ni] = __builtin_amdgcn_mfma_f32_16x16x32_bf16(af[mi], bf[ni], acc[mi][ni], 0, 0, 0);
    __syncthreads();
  }

  if (MODE == 0) {
    unsigned short* C = (unsigned short*)outp;
#pragma unroll
    for (int mi = 0; mi < 4; ++mi) {
      int mb = m0 + wm + mi * 16 + g * 4;
#pragma unroll
      for (int ni = 0; ni < 4; ++ni) {
        int n = n0 + wn + ni * 16 + li;
#pragma unroll
        for (int r = 0; r < 4; ++r)
          C[(size_t)(mb + r) * N + n] = f2bf(acc[mi][ni][r] * scale);
      }
    }
  } else if (MODE == 1) {
    unsigned short* C = (unsigned short*)outp;   // (B*1024) x 2048
#pragma unroll
    for (int mi = 0; mi < 4; ++mi) {
      int mb = m0 + wm + mi * 16 + g * 4;
      int bb = mb >> 11, s = mb & 2047;
#pragma unroll
      for (int ni = 0; ni < 4; ++ni) {
        int n = n0 + wn + ni * 16 + li;
        us4 pk = { f2bf(acc[mi][ni][0]), f2bf(acc[mi][ni][1]),
                   f2bf(acc[mi][ni][2]), f2bf(acc[mi][ni][3]) };
        *(us4*)&C[(size_t)(bb * 1024 + n) * 2048 + s] = pk;
      }
    }
  } else {
    float* C = (float*)outp;
#pragma unroll
    for (int mi = 0; mi < 4; ++mi) {
      int mb = m0 + wm + mi * 16 + g * 4;
#pragma unroll
      for (int ni = 0; ni < 4; ++ni) {
        int n = n0 + wn + ni * 16 + li;
#pragma unroll
        for (int r = 0; r < 4; ++r)
          C[(size_t)(mb + r) * N + n] = acc[mi][ni][r];
      }
    }
  }
}

// ---------------------------------------------------------------- attention v5
// 256 threads = 4 waves. Block owns half-tile pair (tA = x, tB = 31-x): 64 q
// rows each, wave = 16 rows. Every block = exactly 33 iterations, every wave
// active every iteration (ktd == tile for all waves). Grid 1024 = exactly
// 4 blocks/CU fully resident (LDS = 40960 B). K/V double-buffered via
// global_load_lds (XOR-swizzled source), counted vmcnt(4). P in per-wave LDS,
// stride 64 with chunk^(row&7)^(row>>3) XOR swizzle (conflict-free reads).
__global__ __launch_bounds__(256, 4) void attn_kernel(const unsigned short* __restrict__ Qp,
                                                      const unsigned short* __restrict__ Kp,
                                                      const unsigned short* __restrict__ Vt,
                                                      const float* __restrict__ bias,
                                                      const int* __restrict__ flags,
                                                      unsigned short* __restrict__ att) {
  __shared__ unsigned short Klds[2][64 * 64];   // 16 KB
  __shared__ unsigned short Vlds[2][64 * 64];   // 16 KB
  __shared__ unsigned short Plds[4][16 * 64];   //  8 KB  -> total 40960 B

  const int tid = threadIdx.x, lane = tid & 63, w = tid >> 6;   // w in 0..3
  const int g = lane >> 4, li = lane & 15;
  const int b = blockIdx.y >> 4, h = blockIdx.y & 15;
  const int tA = blockIdx.x;                 // 0..15
  const int tB = 31 - tA;                    // 16..31
  const int nA = tA + 1, nTot = nA + tB + 1; // 33 total

  // staging: 512 16B slots per 64x64 tile; thread handles slots tid, tid+256.
  const int s1 = tid, s2 = tid + 256;
  const int r1 = s1 >> 3, c1 = (s1 & 7) ^ (r1 & 7);
  const int r2 = s2 >> 3, c2 = (s2 & 7) ^ (r2 & 7);
  const unsigned short* K1 = Kp + (size_t)(b * 2048 + r1) * 1024 + h * 64 + c1 * 8;
  const unsigned short* K2 = Kp + (size_t)(b * 2048 + r2) * 1024 + h * 64 + c2 * 8;
  const unsigned short* V1 = Vt + (size_t)(b * 1024 + h * 64 + r1) * 2048 + c1 * 8;
  const unsigned short* V2 = Vt + (size_t)(b * 1024 + h * 64 + r2) * 2048 + c2 * 8;

  // K/V fragment read offsets (shorts): row = i*16+li, logical chunk ks*4+g
  int foff[2][4];
#pragma unroll
  for (int ks = 0; ks < 2; ++ks)
#pragma unroll
    for (int i = 0; i < 4; ++i)
      foff[ks][i] = (i * 16 + li) * 64 + (((ks * 4 + g) ^ (li & 7)) * 8);

  // P swizzle: phys_chunk = logical_chunk ^ (row&7) ^ (row>>3); stride 64.
  unsigned short* Pl = &Plds[w][0];
  const int swr = (li & 7) ^ (li >> 3);      // read-side swizzle (row = li)
  int poff[2];                               // PV A-frag read offsets
#pragma unroll
  for (int ks = 0; ks < 2; ++ks) poff[ks] = li * 64 + ((ks * 4 + g) ^ swr) * 8;

  const float* bbase = bias + b * 2048 + li;
  const int*   fbase = flags + b * 32;

  short8 ones;
#pragma unroll
  for (int j = 0; j < 8; ++j) ones[j] = (short)0x3F80;  // bf16 1.0

  int qw = tA * 64 + w * 16;
  short8 qfr[2];
#pragma unroll
  for (int ks = 0; ks < 2; ++ks)
    qfr[ks] = *(const short8*)&Qp[((size_t)(b * 2048 + qw + li)) * 1024 +
                                  h * 64 + ks * 32 + g * 8];

  f32x4 acco[4] = {};
  f32x4 lacc = {};
  float mrow[4] = {-3.0e38f, -3.0e38f, -3.0e38f, -3.0e38f};
  const f32x4 Z = {0.f, 0.f, 0.f, 0.f};

  // prologue: stage kt=0 (tile tA) into buf 0
  g2l16(K1, &Klds[0][w * 512]);
  g2l16(K2, &Klds[0][2048 + w * 512]);
  g2l16(V1, &Vlds[0][w * 512]);
  g2l16(V2, &Vlds[0][2048 + w * 512]);

  int buf = 0;
#pragma unroll 1
  for (int it = 0; it < nTot; ++it) {
    const int kt = (it < nA) ? it : it - nA;

    if (it + 1 < nTot) {
      const int itn = it + 1;
      const size_t ktn = (itn < nA) ? itn : itn - nA;
      g2l16(K1 + ktn * 65536, &Klds[buf ^ 1][w * 512]);
      g2l16(K2 + ktn * 65536, &Klds[buf ^ 1][2048 + w * 512]);
      g2l16(V1 + ktn * 64,    &Vlds[buf ^ 1][w * 512]);
      g2l16(V2 + ktn * 64,    &Vlds[buf ^ 1][2048 + w * 512]);
      asm volatile("s_waitcnt vmcnt(4)" ::: "memory");
    } else {
      asm volatile("s_waitcnt vmcnt(0)" ::: "memory");
    }
    __builtin_amdgcn_s_barrier();

    // ---- QK^T (Q pre-scaled by 1/sqrt(DH)*log2(e); scores in log2 domain)
    f32x4 s[4];
#pragma unroll
    for (int ni = 0; ni < 4; ++ni) {
      short8 kf = *(const short8*)&Klds[buf][foff[0][ni]];
      s[ni] = __builtin_amdgcn_mfma_f32_16x16x32_bf16(qfr[0], kf, Z, 0, 0, 0);
    }
#pragma unroll
    for (int ni = 0; ni < 4; ++ni) {
      short8 kf = *(const short8*)&Klds[buf][foff[1][ni]];
      s[ni] = __builtin_amdgcn_mfma_f32_16x16x32_bf16(qfr[1], kf, s[ni], 0, 0, 0);
    }
    // ---- padding bias (skipped when this 64-key tile is clean)
    if (fbase[kt]) {
#pragma unroll
      for (int ni = 0; ni < 4; ++ni) {
        float bv = bbase[kt * 64 + ni * 16];
#pragma unroll
        for (int r = 0; r < 4; ++r) s[ni][r] += bv;
      }
    }
    // ---- causal mask (diagonal = last iteration of each phase, all waves)
    if (it == nA - 1 || it == nTot - 1) {
      const int q0 = qw + g * 4;
#pragma unroll
      for (int ni = 0; ni < 4; ++ni) {
        const int key = kt * 64 + ni * 16 + li;
#pragma unroll
        for (int r = 0; r < 4; ++r)
          if (key > q0 + r) s[ni][r] = -1.0e9f;
      }
    }
    // ---- tile max per row (in-lane + DPP over 16 key-lanes)
    float tm[4];
#pragma unroll
    for (int r = 0; r < 4; ++r)
      tm[r] = rowmax16(fmaxf(fmaxf(s[0][r], s[1][r]), fmaxf(s[2][r], s[3][r])));
    // ---- defer-max: rescale only when max grew by > 8 (log2 units)
    int need = 0;
#pragma unroll
    for (int r = 0; r < 4; ++r) need |= (tm[r] > mrow[r] + 8.0f) ? 1 : 0;
    if (__any(need)) {
#pragma unroll
      for (int r = 0; r < 4; ++r) {
        const float mn = fmaxf(mrow[r], tm[r]);
        const float al = exp2f(mrow[r] - mn);
        mrow[r] = mn;
        lacc[r] *= al;
#pragma unroll
        for (int df = 0; df < 4; ++df) acco[df][r] *= al;
      }
    }
    // ---- p = exp2(s - m) -> bf16 (cvt_pk) -> swizzled LDS
#pragma unroll
    for (int ni = 0; ni < 4; ++ni) {
#pragma unroll
      for (int h2 = 0; h2 < 2; ++h2) {
        float lo = exp2f(s[ni][2 * h2]     - mrow[2 * h2]);
        float hi = exp2f(s[ni][2 * h2 + 1] - mrow[2 * h2 + 1]);
        unsigned pk = cvt_pk_bf16(lo, hi);
        const int r0 = g * 4 + 2 * h2;
        const int ch = 2 * ni + (li >> 3);
        const int lo7 = li & 7;
        Pl[r0 * 64 + ((ch ^ ((r0 & 7) ^ (g >> 1))) * 8) + lo7] = (unsigned short)pk;
        const int r1_ = r0 + 1;
        Pl[r1_ * 64 + ((ch ^ ((r1_ & 7) ^ (g >> 1))) * 8) + lo7] = (unsigned short)(pk >> 16);
      }
    }
    // ---- PV (+ ones column for row-sum l)
#pragma unroll
    for (int ks = 0; ks < 2; ++ks) {
      const short8 pa = *(const short8*)&Pl[poff[ks]];
      short8 vf[4];
#pragma unroll
      for (int df = 0; df < 4; ++df) vf[df] = *(const short8*)&Vlds[buf][foff[ks][df]];
#pragma unroll
      for (int df = 0; df < 4; ++df)
        acco[df] = __builtin_amdgcn_mfma_f32_16x16x32_bf16(pa, vf[df], acco[df], 0, 0, 0);
      lacc = __builtin_amdgcn_mfma_f32_16x16x32_bf16(pa, ones, lacc, 0, 0, 0);
    }

    __builtin_amdgcn_s_barrier();
    buf ^= 1;

    // ---- per-phase epilogue
    if (it == nA - 1 || it == nTot - 1) {
      float inv[4];
#pragma unroll
      for (int r = 0; r < 4; ++r) inv[r] = 1.0f / lacc[r];
      const int qb0 = qw + g * 4;
#pragma unroll
      for (int df = 0; df < 4; ++df) {
        const int d = h * 64 + df * 16 + li;
#pragma unroll
        for (int r = 0; r < 4; ++r)
          att[(size_t)(b * 2048 + qb0 + r) * 1024 + d] = f2bf(acco[df][r] * inv[r]);
      }
      if (it == nA - 1) {
        qw = tB * 64 + w * 16;
#pragma unroll
        for (int ks = 0; ks < 2; ++ks)
          qfr[ks] = *(const short8*)&Qp[((size_t)(b * 2048 + qw + li)) * 1024 +
                                        h * 64 + ks * 32 + g * 8];
#pragma unroll
        for (int df = 0; df < 4; ++df) acco[df] = Z;
        lacc = Z;
#pragma unroll
        for (int r = 0; r < 4; ++r) mrow[r] = -3.0e38f;
      }
    }
  }
}

// ---------------------------------------------------------------- launch
extern "C" void kernel_launch(void* const* d_in, const int* in_sizes, int n_in,
                              void* d_out, int out_size, void* d_ws, size_t ws_size,
                              hipStream_t stream) {
  const float* q_raw  = (const float*)d_in[0];
  const float* kv_raw = (const float*)d_in[1];
  const int*   pmask  = (const int*)d_in[2];
  const float* Wq = (const float*)d_in[3];
  const float* Wk = (const float*)d_in[4];
  const float* Wv = (const float*)d_in[5];
  const float* Wo = (const float*)d_in[6];
  float* out = (float*)d_out;

  const size_t NEL = 8388608;   // B*S*D
  const size_t WEL = 1048576;   // D*D
  unsigned short* ws   = (unsigned short*)d_ws;
  unsigned short* qbf  = ws;              // reused as att after projections
  unsigned short* kvbf = qbf + NEL;
  unsigned short* wbf  = kvbf + NEL;      // Wq,Wk,Wv,Wo bf16 back-to-back
  unsigned short* Qp   = wbf + 4 * WEL;
  unsigned short* Kp   = Qp + NEL;
  unsigned short* Vtp  = Kp + NEL;        // (B,H,DH,S) transposed V
  float*          bias = (float*)(Vtp + NEL);
  int*            flags = (int*)(bias + 8192);
  unsigned short* att  = qbf;             // alias (qbf dead after projections)

  const float sc = 0.125f * 1.44269504088896340736f;  // 1/sqrt(DH) * log2(e)

  cvt_kernel<<<2048, 256, 0, stream>>>(q_raw,  qbf,  (int)(NEL / 4));
  cvt_kernel<<<2048, 256, 0, stream>>>(kv_raw, kvbf, (int)(NEL / 4));
  cvt_kernel<<<256, 256, 0, stream>>>(Wq, wbf,           (int)(WEL / 4));
  cvt_kernel<<<256, 256, 0, stream>>>(Wk, wbf + WEL,     (int)(WEL / 4));
  cvt_kernel<<<256, 256, 0, stream>>>(Wv, wbf + 2 * WEL, (int)(WEL / 4));
  cvt_kernel<<<256, 256, 0, stream>>>(Wo, wbf + 3 * WEL, (int)(WEL / 4));
  bias_kernel<<<128, 64, 0, stream>>>(pmask, bias, flags);

  dim3 gg(8, 64);  // N/128, M/128
  gemm_nt<0><<<gg, 256, 0, stream>>>(qbf,  wbf,           (void*)Qp,  8192, 1024, 1024, sc);
  gemm_nt<0><<<gg, 256, 0, stream>>>(kvbf, wbf + WEL,     (void*)Kp,  8192, 1024, 1024, 1.0f);
  gemm_nt<1><<<gg, 256, 0, stream>>>(kvbf, wbf + 2 * WEL, (void*)Vtp, 8192, 1024, 1024, 1.0f);

  attn_kernel<<<dim3(16, 64), 256, 0, stream>>>(Qp, Kp, Vtp, bias, flags, att);

  gemm_nt<2><<<gg, 256, 0, stream>>>(att, wbf + 3 * WEL, (void*)out, 8192, 1024, 1024, 1.0f);
}

// Round 6
// 211.407 us; speedup vs baseline: 1.5583x; 1.1662x over previous
//
#include <hip/hip_runtime.h>
#include <stdint.h>

typedef __attribute__((ext_vector_type(8))) short  short8;   // 8 bf16 = 4 VGPR MFMA frag
typedef __attribute__((ext_vector_type(4))) float  f32x4;    // MFMA accumulator
typedef __attribute__((ext_vector_type(4))) unsigned short us4;

static __device__ __forceinline__ unsigned short f2bf(float x) {
  unsigned u = __builtin_bit_cast(unsigned, x);
  u += 0x7FFFu + ((u >> 16) & 1u);          // round-to-nearest-even
  return (unsigned short)(u >> 16);
}

static __device__ __forceinline__ unsigned cvt_pk_bf16(float lo, float hi) {
  unsigned r;
  asm("v_cvt_pk_bf16_f32 %0, %1, %2" : "=v"(r) : "v"(lo), "v"(hi));
  return r;
}

// max with DPP-shuffled self (reduction over 16-lane row)
template <int CTRL>
static __device__ __forceinline__ float maxdpp(float v) {
  int o = __builtin_amdgcn_update_dpp(0, __builtin_bit_cast(int, v), CTRL, 0xf, 0xf, false);
  return fmaxf(v, __builtin_bit_cast(float, o));
}
static __device__ __forceinline__ float rowmax16(float v) {
  v = maxdpp<0xB1>(v);    // quad_perm xor 1
  v = maxdpp<0x4E>(v);    // quad_perm xor 2
  v = maxdpp<0x141>(v);   // row_half_mirror
  v = maxdpp<0x140>(v);   // row_mirror
  return v;
}

// ------------------------------------------------- fp32 -> bf16 (6 regions)
__global__ __launch_bounds__(256) void cvt6(const float* __restrict__ q_raw,
                                            const float* __restrict__ kv_raw,
                                            const float* __restrict__ Wq,
                                            const float* __restrict__ Wk,
                                            const float* __restrict__ Wv,
                                            const float* __restrict__ Wo,
                                            unsigned short* __restrict__ qbf,
                                            unsigned short* __restrict__ kvbf,
                                            unsigned short* __restrict__ wbf) {
  const int y = blockIdx.y;
  const float* in;
  unsigned short* out;
  int n4;
  if (y == 0)      { in = q_raw;  out = qbf;  n4 = 2097152; }
  else if (y == 1) { in = kv_raw; out = kvbf; n4 = 2097152; }
  else {
    in  = (y == 2) ? Wq : (y == 3) ? Wk : (y == 4) ? Wv : Wo;
    out = wbf + (size_t)(y - 2) * 1048576;
    n4 = 262144;
  }
  int i = blockIdx.x * 256 + threadIdx.x;
  const int stride = gridDim.x * 256;
  for (; i < n4; i += stride) {
    f32x4 v = *((const f32x4*)in + i);
    us4 o = { f2bf(v[0]), f2bf(v[1]), f2bf(v[2]), f2bf(v[3]) };
    *((us4*)out + i) = o;
  }
}

// ---------------------- pmask -> f32 bias + per-batch 32-bit dirty-tile mask
__global__ __launch_bounds__(1024) void bias_kernel(const int* __restrict__ pm,
                                                    float* __restrict__ bias,
                                                    unsigned* __restrict__ flagmask) {
  __shared__ unsigned m;
  const int b = blockIdx.x, tid = threadIdx.x;
  if (tid == 0) m = 0;
  __syncthreads();
  const int i0 = b * 2048 + tid;
  const int z0 = pm[i0], z1 = pm[i0 + 1024];
  bias[i0]        = z0 ? 0.f : -1.0e9f;
  bias[i0 + 1024] = z1 ? 0.f : -1.0e9f;
  const int wv = tid >> 6;                  // wave index 0..15 = tile index
  unsigned long long b0 = __ballot(z0 == 0);
  unsigned long long b1 = __ballot(z1 == 0);
  if ((tid & 63) == 0) {
    unsigned bits = (b0 ? (1u << wv) : 0u) | (b1 ? (1u << (wv + 16)) : 0u);
    if (bits) atomicOr(&m, bits);
  }
  __syncthreads();
  if (tid == 0) flagmask[b] = m;
}

// ------------------------------------------------------- async global->LDS 16B
static __device__ __forceinline__ void g2l16(const void* g, void* l) {
  __builtin_amdgcn_global_load_lds(
      (const __attribute__((address_space(1))) void*)g,
      (__attribute__((address_space(3))) void*)l, 16, 0, 0);
}

// ------------------------------------------- fused Q/K/V projection NT GEMM
// grid (24, 64): x>>3 = region (0=Q,1=K,2=V), x&7 = n-tile, y = m-tile.
// BM=BN=128, BK=32, 256 threads = 4 waves (2x2), 64x64 per wave. K=N=1024.
__global__ __launch_bounds__(256) void gemm_proj(const unsigned short* __restrict__ qbf,
                                                 const unsigned short* __restrict__ kvbf,
                                                 const unsigned short* __restrict__ wbf,
                                                 unsigned short* __restrict__ Qp,
                                                 unsigned short* __restrict__ Kp,
                                                 unsigned short* __restrict__ Vtp,
                                                 float qscale) {
  __shared__ unsigned short Alds[128 * 32];
  __shared__ unsigned short Blds[128 * 32];
  const int tid  = threadIdx.x;
  const int lane = tid & 63;
  const int w    = tid >> 6;
  const int g    = lane >> 4;
  const int li   = lane & 15;
  const int x = blockIdx.x;
  const int region = x >> 3;
  const int n0 = (x & 7) * 128;
  const int m0 = blockIdx.y * 128;
  const int wm = (w >> 1) * 64;
  const int wn = (w & 1) * 64;

  const unsigned short* A = (region == 0) ? qbf : kvbf;
  const unsigned short* W = wbf + (size_t)region * 1048576;

  int aoff[4], boff[4];
#pragma unroll
  for (int mi = 0; mi < 4; ++mi) {
    int row = wm + mi * 16 + li;
    aoff[mi] = row * 32 + (g ^ ((row >> 1) & 3)) * 8;
  }
#pragma unroll
  for (int ni = 0; ni < 4; ++ni) {
    int col = wn + ni * 16 + li;
    boff[ni] = col * 32 + (g ^ ((col >> 1) & 3)) * 8;
  }

  const int s1 = tid, s2 = 256 + tid;
  const int r1 = s1 >> 2, gc1 = (s1 & 3) ^ ((r1 >> 1) & 3);
  const int r2 = s2 >> 2, gc2 = (s2 & 3) ^ ((r2 >> 1) & 3);
  const unsigned short* gA1 = A + (size_t)(m0 + r1) * 1024 + gc1 * 8;
  const unsigned short* gA2 = A + (size_t)(m0 + r2) * 1024 + gc2 * 8;
  const unsigned short* gB1 = W + (size_t)(n0 + r1) * 1024 + gc1 * 8;
  const unsigned short* gB2 = W + (size_t)(n0 + r2) * 1024 + gc2 * 8;
  unsigned short* lA1 = &Alds[w * 512];
  unsigned short* lA2 = &Alds[2048 + w * 512];
  unsigned short* lB1 = &Blds[w * 512];
  unsigned short* lB2 = &Blds[2048 + w * 512];

  f32x4 acc[4][4] = {};

#pragma unroll 1
  for (int kt = 0; kt < 32; ++kt) {
    g2l16(gA1, lA1); g2l16(gA2, lA2);
    g2l16(gB1, lB1); g2l16(gB2, lB2);
    gA1 += 32; gA2 += 32; gB1 += 32; gB2 += 32;
    asm volatile("s_waitcnt vmcnt(0)" ::: "memory");
    __syncthreads();
    short8 af[4], bf[4];
#pragma unroll
    for (int mi = 0; mi < 4; ++mi) af[mi] = *(const short8*)&Alds[aoff[mi]];
#pragma unroll
    for (int ni = 0; ni < 4; ++ni) bf[ni] = *(const short8*)&Blds[boff[ni]];
#pragma unroll
    for (int mi = 0; mi < 4; ++mi)
#pragma unroll
      for (int ni = 0; ni < 4; ++ni)
        acc[mi][ni] = __builtin_amdgcn_mfma_f32_16x16x32_bf16(af[mi], bf[ni], acc[mi][ni], 0, 0, 0);
    __syncthreads();
  }

  if (region == 2) {
    // V: transposed bf16 out -> Vtp[(b*1024 + n)*2048 + s]
#pragma unroll
    for (int mi = 0; mi < 4; ++mi) {
      int mb = m0 + wm + mi * 16 + g * 4;
      int bb = mb >> 11, s = mb & 2047;
#pragma unroll
      for (int ni = 0; ni < 4; ++ni) {
        int n = n0 + wn + ni * 16 + li;
        us4 pk = { f2bf(acc[mi][ni][0]), f2bf(acc[mi][ni][1]),
                   f2bf(acc[mi][ni][2]), f2bf(acc[mi][ni][3]) };
        *(us4*)&Vtp[(size_t)(bb * 1024 + n) * 2048 + s] = pk;
      }
    }
  } else {
    unsigned short* C = (region == 0) ? Qp : Kp;
    const float sc = (region == 0) ? qscale : 1.0f;
#pragma unroll
    for (int mi = 0; mi < 4; ++mi) {
      int mb = m0 + wm + mi * 16 + g * 4;
#pragma unroll
      for (int ni = 0; ni < 4; ++ni) {
        int n = n0 + wn + ni * 16 + li;
#pragma unroll
        for (int r = 0; r < 4; ++r)
          C[(size_t)(mb + r) * 1024 + n] = f2bf(acc[mi][ni][r] * sc);
      }
    }
  }
}

// ------------------------------------------------------- output projection GEMM
// C[m][n] = sum_k att[m][k] * Wo[n][k], fp32 out. M=8192, N=K=1024.
__global__ __launch_bounds__(256) void gemm_out(const unsigned short* __restrict__ A,
                                                const unsigned short* __restrict__ W,
                                                float* __restrict__ C) {
  __shared__ unsigned short Alds[128 * 32];
  __shared__ unsigned short Blds[128 * 32];
  const int tid  = threadIdx.x;
  const int lane = tid & 63;
  const int w    = tid >> 6;
  const int g    = lane >> 4;
  const int li   = lane & 15;
  const int m0 = blockIdx.y * 128;
  const int n0 = blockIdx.x * 128;
  const int wm = (w >> 1) * 64;
  const int wn = (w & 1) * 64;

  int aoff[4], boff[4];
#pragma unroll
  for (int mi = 0; mi < 4; ++mi) {
    int row = wm + mi * 16 + li;
    aoff[mi] = row * 32 + (g ^ ((row >> 1) & 3)) * 8;
  }
#pragma unroll
  for (int ni = 0; ni < 4; ++ni) {
    int col = wn + ni * 16 + li;
    boff[ni] = col * 32 + (g ^ ((col >> 1) & 3)) * 8;
  }

  const int s1 = tid, s2 = 256 + tid;
  const int r1 = s1 >> 2, gc1 = (s1 & 3) ^ ((r1 >> 1) & 3);
  const int r2 = s2 >> 2, gc2 = (s2 & 3) ^ ((r2 >> 1) & 3);
  const unsigned short* gA1 = A + (size_t)(m0 + r1) * 1024 + gc1 * 8;
  const unsigned short* gA2 = A + (size_t)(m0 + r2) * 1024 + gc2 * 8;
  const unsigned short* gB1 = W + (size_t)(n0 + r1) * 1024 + gc1 * 8;
  const unsigned short* gB2 = W + (size_t)(n0 + r2) * 1024 + gc2 * 8;
  unsigned short* lA1 = &Alds[w * 512];
  unsigned short* lA2 = &Alds[2048 + w * 512];
  unsigned short* lB1 = &Blds[w * 512];
  unsigned short* lB2 = &Blds[2048 + w * 512];

  f32x4 acc[4][4] = {};

#pragma unroll 1
  for (int kt = 0; kt < 32; ++kt) {
    g2l16(gA1, lA1); g2l16(gA2, lA2);
    g2l16(gB1, lB1); g2l16(gB2, lB2);
    gA1 += 32; gA2 += 32; gB1 += 32; gB2 += 32;
    asm volatile("s_waitcnt vmcnt(0)" ::: "memory");
    __syncthreads();
    short8 af[4], bf[4];
#pragma unroll
    for (int mi = 0; mi < 4; ++mi) af[mi] = *(const short8*)&Alds[aoff[mi]];
#pragma unroll
    for (int ni = 0; ni < 4; ++ni) bf[ni] = *(const short8*)&Blds[boff[ni]];
#pragma unroll
    for (int mi = 0; mi < 4; ++mi)
#pragma unroll
      for (int ni = 0; ni < 4; ++ni)
        acc[mi][ni] = __builtin_amdgcn_mfma_f32_16x16x32_bf16(af[mi], bf[ni], acc[mi][ni], 0, 0, 0);
    __syncthreads();
  }

#pragma unroll
  for (int mi = 0; mi < 4; ++mi) {
    int mb = m0 + wm + mi * 16 + g * 4;
#pragma unroll
    for (int ni = 0; ni < 4; ++ni) {
      int n = n0 + wn + ni * 16 + li;
#pragma unroll
      for (int r = 0; r < 4; ++r)
        C[(size_t)(mb + r) * 1024 + n] = acc[mi][ni][r];
    }
  }
}

// ---------------------------------------------------------------- attention v6
// 256 threads = 4 waves; block owns half-tile pair (tA, 31-tA): 33 iterations
// uniform; grid 1024 = exactly 4 blocks/CU resident. XCD-affine remap: each
// (b,h) is processed entirely on ONE XCD (8 heads/XCD, K+V = 4 MB = one L2).
__global__ __launch_bounds__(256, 4) void attn_kernel(const unsigned short* __restrict__ Qp,
                                                      const unsigned short* __restrict__ Kp,
                                                      const unsigned short* __restrict__ Vt,
                                                      const float* __restrict__ bias,
                                                      const unsigned* __restrict__ flagmask,
                                                      unsigned short* __restrict__ att) {
  __shared__ unsigned short Klds[2][64 * 64];   // 16 KB
  __shared__ unsigned short Vlds[2][64 * 64];   // 16 KB
  __shared__ unsigned short Plds[4][16 * 64];   //  8 KB -> 40960 B total

  const int tid = threadIdx.x, lane = tid & 63, w = tid >> 6;
  const int g = lane >> 4, li = lane & 15;

  // XCD-affine block remap (XCD = linear_block_id % 8 on MI355X)
  const int rid = blockIdx.x + (blockIdx.y << 4);
  const int xcd = rid & 7, kk = rid >> 3;
  const int bh = (kk & 7) | (xcd << 3);
  const int b = bh >> 4, h = bh & 15;
  const int tA = kk >> 3, tB = 31 - tA;
  const int nA = tA + 1, nB = tB + 1;

  const unsigned smask = flagmask[b];

  // staging source lanes: 512 16B slots per 64x64 tile; thread = slots tid, tid+256
  const int s1 = tid, s2 = tid + 256;
  const int r1 = s1 >> 3, c1 = (s1 & 7) ^ (r1 & 7);
  const int r2 = s2 >> 3, c2 = (s2 & 7) ^ (r2 & 7);
  const unsigned short* Kb1 = Kp + (size_t)(b * 2048 + r1) * 1024 + h * 64 + c1 * 8;
  const unsigned short* Kb2 = Kp + (size_t)(b * 2048 + r2) * 1024 + h * 64 + c2 * 8;
  const unsigned short* Vb1 = Vt + (size_t)(b * 1024 + h * 64 + r1) * 2048 + c1 * 8;
  const unsigned short* Vb2 = Vt + (size_t)(b * 1024 + h * 64 + r2) * 2048 + c2 * 8;

  int foff[2][4];
#pragma unroll
  for (int ks = 0; ks < 2; ++ks)
#pragma unroll
    for (int i = 0; i < 4; ++i)
      foff[ks][i] = (i * 16 + li) * 64 + (((ks * 4 + g) ^ (li & 7)) * 8);

  unsigned short* Pl = &Plds[w][0];
  const int swr = (li & 7) ^ (li >> 3);
  int poff[2];
#pragma unroll
  for (int ks = 0; ks < 2; ++ks) poff[ks] = li * 64 + ((ks * 4 + g) ^ swr) * 8;

  const float* bbase = bias + b * 2048 + li;

  short8 ones;
#pragma unroll
  for (int j = 0; j < 8; ++j) ones[j] = (short)0x3F80;  // bf16 1.0

  int qw = tA * 64 + w * 16;
  short8 qfr[2];
#pragma unroll
  for (int ks = 0; ks < 2; ++ks)
    qfr[ks] = *(const short8*)&Qp[((size_t)(b * 2048 + qw + li)) * 1024 +
                                  h * 64 + ks * 32 + g * 8];

  f32x4 acco[4] = {};
  f32x4 lacc = {};
  float mrow[4] = {-3.0e38f, -3.0e38f, -3.0e38f, -3.0e38f};
  const f32x4 Z = {0.f, 0.f, 0.f, 0.f};

  auto stage = [&](int kt, int bufn) {
    const size_t ko = (size_t)kt * 65536, vo = (size_t)kt * 64;
    g2l16(Kb1 + ko, &Klds[bufn][w * 512]);
    g2l16(Kb2 + ko, &Klds[bufn][2048 + w * 512]);
    g2l16(Vb1 + vo, &Vlds[bufn][w * 512]);
    g2l16(Vb2 + vo, &Vlds[bufn][2048 + w * 512]);
  };

  auto body = [&](int kt, bool diag, int buf) {
    // ---- QK^T (Q pre-scaled; scores in log2 domain)
    f32x4 s[4];
#pragma unroll
    for (int ni = 0; ni < 4; ++ni) {
      short8 kf = *(const short8*)&Klds[buf][foff[0][ni]];
      s[ni] = __builtin_amdgcn_mfma_f32_16x16x32_bf16(qfr[0], kf, Z, 0, 0, 0);
    }
#pragma unroll
    for (int ni = 0; ni < 4; ++ni) {
      short8 kf = *(const short8*)&Klds[buf][foff[1][ni]];
      s[ni] = __builtin_amdgcn_mfma_f32_16x16x32_bf16(qfr[1], kf, s[ni], 0, 0, 0);
    }
    // ---- padding bias (scalar-gated; all-clean batches never enter)
    if ((smask >> kt) & 1u) {
#pragma unroll
      for (int ni = 0; ni < 4; ++ni) {
        float bv = bbase[kt * 64 + ni * 16];
#pragma unroll
        for (int r = 0; r < 4; ++r) s[ni][r] += bv;
      }
    }
    // ---- causal mask (diagonal iteration only)
    if (diag) {
      const int q0 = qw + g * 4;
#pragma unroll
      for (int ni = 0; ni < 4; ++ni) {
        const int key = kt * 64 + ni * 16 + li;
#pragma unroll
        for (int r = 0; r < 4; ++r)
          if (key > q0 + r) s[ni][r] = -1.0e9f;
      }
    }
    // ---- tile max per row
    float tm[4];
#pragma unroll
    for (int r = 0; r < 4; ++r)
      tm[r] = rowmax16(fmaxf(fmaxf(s[0][r], s[1][r]), fmaxf(s[2][r], s[3][r])));
    // ---- defer-max rescale
    int need = 0;
#pragma unroll
    for (int r = 0; r < 4; ++r) need |= (tm[r] > mrow[r] + 8.0f) ? 1 : 0;
    if (__any(need)) {
#pragma unroll
      for (int r = 0; r < 4; ++r) {
        const float mn = fmaxf(mrow[r], tm[r]);
        const float al = __builtin_amdgcn_exp2f(mrow[r] - mn);
        mrow[r] = mn;
        lacc[r] *= al;
#pragma unroll
        for (int df = 0; df < 4; ++df) acco[df][r] *= al;
      }
    }
    // ---- p = exp2(s - m) -> bf16 -> swizzled LDS
#pragma unroll
    for (int ni = 0; ni < 4; ++ni) {
#pragma unroll
      for (int h2 = 0; h2 < 2; ++h2) {
        float lo = __builtin_amdgcn_exp2f(s[ni][2 * h2]     - mrow[2 * h2]);
        float hi = __builtin_amdgcn_exp2f(s[ni][2 * h2 + 1] - mrow[2 * h2 + 1]);
        unsigned pk = cvt_pk_bf16(lo, hi);
        const int r0 = g * 4 + 2 * h2;
        const int ch = 2 * ni + (li >> 3);
        const int lo7 = li & 7;
        Pl[r0 * 64 + ((ch ^ ((r0 & 7) ^ (g >> 1))) * 8) + lo7] = (unsigned short)pk;
        const int rr = r0 + 1;
        Pl[rr * 64 + ((ch ^ ((rr & 7) ^ (g >> 1))) * 8) + lo7] = (unsigned short)(pk >> 16);
      }
    }
    // ---- PV (+ ones column for row-sum l)
#pragma unroll
    for (int ks = 0; ks < 2; ++ks) {
      const short8 pa = *(const short8*)&Pl[poff[ks]];
      short8 vf[4];
#pragma unroll
      for (int df = 0; df < 4; ++df) vf[df] = *(const short8*)&Vlds[buf][foff[ks][df]];
#pragma unroll
      for (int df = 0; df < 4; ++df)
        acco[df] = __builtin_amdgcn_mfma_f32_16x16x32_bf16(pa, vf[df], acco[df], 0, 0, 0);
      lacc = __builtin_amdgcn_mfma_f32_16x16x32_bf16(pa, ones, lacc, 0, 0, 0);
    }
  };

  auto epilogue = [&]() {
    float inv[4];
#pragma unroll
    for (int r = 0; r < 4; ++r) inv[r] = __builtin_amdgcn_rcpf(lacc[r]);
    const int qb0 = qw + g * 4;
#pragma unroll
    for (int df = 0; df < 4; ++df) {
      const int d = h * 64 + df * 16 + li;
#pragma unroll
      for (int r = 0; r < 4; ++r)
        att[(size_t)(b * 2048 + qb0 + r) * 1024 + d] = f2bf(acco[df][r] * inv[r]);
    }
  };

  // prologue: stage tile 0 into buf 0
  stage(0, 0);
  int buf = 0;

#pragma unroll 1
  for (int kt = 0; kt < nA; ++kt) {
    stage((kt + 1 < nA) ? kt + 1 : 0, buf ^ 1);   // last A-iter prefetches B's tile 0
    asm volatile("s_waitcnt vmcnt(4)" ::: "memory");
    __builtin_amdgcn_s_barrier();
    body(kt, kt == nA - 1, buf);
    __builtin_amdgcn_s_barrier();
    buf ^= 1;
  }

  epilogue();
  qw = tB * 64 + w * 16;
#pragma unroll
  for (int ks = 0; ks < 2; ++ks)
    qfr[ks] = *(const short8*)&Qp[((size_t)(b * 2048 + qw + li)) * 1024 +
                                  h * 64 + ks * 32 + g * 8];
#pragma unroll
  for (int df = 0; df < 4; ++df) acco[df] = Z;
  lacc = Z;
#pragma unroll
  for (int r = 0; r < 4; ++r) mrow[r] = -3.0e38f;

#pragma unroll 1
  for (int kt = 0; kt < nB; ++kt) {
    if (kt + 1 < nB) {
      stage(kt + 1, buf ^ 1);
      asm volatile("s_waitcnt vmcnt(4)" ::: "memory");
    } else {
      asm volatile("s_waitcnt vmcnt(0)" ::: "memory");
    }
    __builtin_amdgcn_s_barrier();
    body(kt, kt == nB - 1, buf);
    __builtin_amdgcn_s_barrier();
    buf ^= 1;
  }

  epilogue();
}

// ---------------------------------------------------------------- launch
extern "C" void kernel_launch(void* const* d_in, const int* in_sizes, int n_in,
                              void* d_out, int out_size, void* d_ws, size_t ws_size,
                              hipStream_t stream) {
  const float* q_raw  = (const float*)d_in[0];
  const float* kv_raw = (const float*)d_in[1];
  const int*   pmask  = (const int*)d_in[2];
  const float* Wq = (const float*)d_in[3];
  const float* Wk = (const float*)d_in[4];
  const float* Wv = (const float*)d_in[5];
  const float* Wo = (const float*)d_in[6];
  float* out = (float*)d_out;

  const size_t NEL = 8388608;   // B*S*D
  const size_t WEL = 1048576;   // D*D
  unsigned short* ws   = (unsigned short*)d_ws;
  unsigned short* qbf  = ws;              // reused as att after projections
  unsigned short* kvbf = qbf + NEL;
  unsigned short* wbf  = kvbf + NEL;      // Wq,Wk,Wv,Wo bf16 back-to-back
  unsigned short* Qp   = wbf + 4 * WEL;
  unsigned short* Kp   = Qp + NEL;
  unsigned short* Vtp  = Kp + NEL;        // (B,H,DH,S) transposed V
  float*          bias = (float*)(Vtp + NEL);
  unsigned*       flagmask = (unsigned*)(bias + 8192);
  unsigned short* att  = qbf;             // alias (qbf dead after projections)

  const float sc = 0.125f * 1.44269504088896340736f;  // 1/sqrt(DH) * log2(e)

  cvt6<<<dim3(512, 6), 256, 0, stream>>>(q_raw, kv_raw, Wq, Wk, Wv, Wo, qbf, kvbf, wbf);
  bias_kernel<<<4, 1024, 0, stream>>>(pmask, bias, flagmask);
  gemm_proj<<<dim3(24, 64), 256, 0, stream>>>(qbf, kvbf, wbf, Qp, Kp, Vtp, sc);
  attn_kernel<<<dim3(16, 64), 256, 0, stream>>>(Qp, Kp, Vtp, bias, flagmask, att);
  gemm_out<<<dim3(8, 64), 256, 0, stream>>>(att, wbf + 3 * WEL, out);
}

// Round 7
// 191.206 us; speedup vs baseline: 1.7229x; 1.1056x over previous
//
#include <hip/hip_runtime.h>
#include <stdint.h>

typedef __attribute__((ext_vector_type(8))) short  short8;   // 8 bf16 = 4 VGPR MFMA frag
typedef __attribute__((ext_vector_type(4))) float  f32x4;    // MFMA accumulator
typedef __attribute__((ext_vector_type(4))) unsigned short us4;

static __device__ __forceinline__ unsigned short f2bf(float x) {
  unsigned u = __builtin_bit_cast(unsigned, x);
  u += 0x7FFFu + ((u >> 16) & 1u);          // round-to-nearest-even
  return (unsigned short)(u >> 16);
}

static __device__ __forceinline__ unsigned cvt_pk_bf16(float lo, float hi) {
  unsigned r;
  asm("v_cvt_pk_bf16_f32 %0, %1, %2" : "=v"(r) : "v"(lo), "v"(hi));
  return r;
}

// max with DPP-shuffled self (reduction over 16-lane row)
template <int CTRL>
static __device__ __forceinline__ float maxdpp(float v) {
  int o = __builtin_amdgcn_update_dpp(0, __builtin_bit_cast(int, v), CTRL, 0xf, 0xf, false);
  return fmaxf(v, __builtin_bit_cast(float, o));
}
static __device__ __forceinline__ float rowmax16(float v) {
  v = maxdpp<0xB1>(v);    // quad_perm xor 1
  v = maxdpp<0x4E>(v);    // quad_perm xor 2
  v = maxdpp<0x141>(v);   // row_half_mirror
  v = maxdpp<0x140>(v);   // row_mirror
  return v;
}

// ------------------------------------------------- fp32 -> bf16 (6 regions)
__global__ __launch_bounds__(256) void cvt6(const float* __restrict__ q_raw,
                                            const float* __restrict__ kv_raw,
                                            const float* __restrict__ Wq,
                                            const float* __restrict__ Wk,
                                            const float* __restrict__ Wv,
                                            const float* __restrict__ Wo,
                                            unsigned short* __restrict__ qbf,
                                            unsigned short* __restrict__ kvbf,
                                            unsigned short* __restrict__ wbf) {
  const int y = blockIdx.y;
  const float* in;
  unsigned short* out;
  int n4;
  if (y == 0)      { in = q_raw;  out = qbf;  n4 = 2097152; }
  else if (y == 1) { in = kv_raw; out = kvbf; n4 = 2097152; }
  else {
    in  = (y == 2) ? Wq : (y == 3) ? Wk : (y == 4) ? Wv : Wo;
    out = wbf + (size_t)(y - 2) * 1048576;
    n4 = 262144;
  }
  int i = blockIdx.x * 256 + threadIdx.x;
  const int stride = gridDim.x * 256;
  for (; i < n4; i += stride) {
    f32x4 v = *((const f32x4*)in + i);
    us4 o = { f2bf(v[0]), f2bf(v[1]), f2bf(v[2]), f2bf(v[3]) };
    *((us4*)out + i) = o;
  }
}

// ---------------------- pmask -> f32 bias + per-batch 32-bit dirty-tile mask
__global__ __launch_bounds__(1024) void bias_kernel(const int* __restrict__ pm,
                                                    float* __restrict__ bias,
                                                    unsigned* __restrict__ flagmask) {
  __shared__ unsigned m;
  const int b = blockIdx.x, tid = threadIdx.x;
  if (tid == 0) m = 0;
  __syncthreads();
  const int i0 = b * 2048 + tid;
  const int z0 = pm[i0], z1 = pm[i0 + 1024];
  bias[i0]        = z0 ? 0.f : -1.0e9f;
  bias[i0 + 1024] = z1 ? 0.f : -1.0e9f;
  const int wv = tid >> 6;                  // wave index 0..15 = tile index
  unsigned long long b0 = __ballot(z0 == 0);
  unsigned long long b1 = __ballot(z1 == 0);
  if ((tid & 63) == 0) {
    unsigned bits = (b0 ? (1u << wv) : 0u) | (b1 ? (1u << (wv + 16)) : 0u);
    if (bits) atomicOr(&m, bits);
  }
  __syncthreads();
  if (tid == 0) flagmask[b] = m;
}

// ------------------------------------------------------- async global->LDS 16B
static __device__ __forceinline__ void g2l16(const void* g, void* l) {
  __builtin_amdgcn_global_load_lds(
      (const __attribute__((address_space(1))) void*)g,
      (__attribute__((address_space(3))) void*)l, 16, 0, 0);
}

// ------------------------------------------- fused Q/K/V projection NT GEMM
// Linear grid of 1536. XCD-affine map: xcd = l&7 owns m-tiles [8*xcd, 8*xcd+8)
// for ALL (region, n) -> per-XCD A working set = 4 MB (one L2). Per-XCD order:
// mstep fastest, (region,n) slow. 2-phase double-buffered staging pipeline.
__global__ __launch_bounds__(256) void gemm_proj(const unsigned short* __restrict__ qbf,
                                                 const unsigned short* __restrict__ kvbf,
                                                 const unsigned short* __restrict__ wbf,
                                                 unsigned short* __restrict__ Qp,
                                                 unsigned short* __restrict__ Kp,
                                                 unsigned short* __restrict__ Vtp,
                                                 float qscale) {
  __shared__ unsigned short Alds[2][4096];
  __shared__ unsigned short Blds[2][4096];
  const int tid  = threadIdx.x;
  const int lane = tid & 63;
  const int w    = tid >> 6;
  const int g    = lane >> 4;
  const int li   = lane & 15;

  const int l = blockIdx.x;
  const int xcd = l & 7, j = l >> 3;
  const int mstep = j & 7, rn = j >> 3;     // rn in [0,24)
  const int region = rn >> 3;               // 0=Q, 1=K, 2=V
  const int n0 = (rn & 7) * 128;
  const int m0 = (xcd * 8 + mstep) * 128;
  const int wm = (w >> 1) * 64;
  const int wn = (w & 1) * 64;

  const unsigned short* A = (region == 0) ? qbf : kvbf;
  const unsigned short* W = wbf + (size_t)region * 1048576;

  int aoff[4], boff[4];
#pragma unroll
  for (int mi = 0; mi < 4; ++mi) {
    int row = wm + mi * 16 + li;
    aoff[mi] = row * 32 + (g ^ ((row >> 1) & 3)) * 8;
  }
#pragma unroll
  for (int ni = 0; ni < 4; ++ni) {
    int col = wn + ni * 16 + li;
    boff[ni] = col * 32 + (g ^ ((col >> 1) & 3)) * 8;
  }

  const int s1 = tid, s2 = 256 + tid;
  const int r1 = s1 >> 2, gc1 = (s1 & 3) ^ ((r1 >> 1) & 3);
  const int r2 = s2 >> 2, gc2 = (s2 & 3) ^ ((r2 >> 1) & 3);
  const unsigned short* gA1 = A + (size_t)(m0 + r1) * 1024 + gc1 * 8;
  const unsigned short* gA2 = A + (size_t)(m0 + r2) * 1024 + gc2 * 8;
  const unsigned short* gB1 = W + (size_t)(n0 + r1) * 1024 + gc1 * 8;
  const unsigned short* gB2 = W + (size_t)(n0 + r2) * 1024 + gc2 * 8;

  f32x4 acc[4][4] = {};

  // prologue: stage tile 0 into buf 0
  g2l16(gA1, &Alds[0][w * 512]); g2l16(gA2, &Alds[0][2048 + w * 512]);
  g2l16(gB1, &Blds[0][w * 512]); g2l16(gB2, &Blds[0][2048 + w * 512]);
  gA1 += 32; gA2 += 32; gB1 += 32; gB2 += 32;

  int cur = 0;
#pragma unroll 1
  for (int kt = 0; kt < 32; ++kt) {
    if (kt < 31) {
      g2l16(gA1, &Alds[cur ^ 1][w * 512]); g2l16(gA2, &Alds[cur ^ 1][2048 + w * 512]);
      g2l16(gB1, &Blds[cur ^ 1][w * 512]); g2l16(gB2, &Blds[cur ^ 1][2048 + w * 512]);
      gA1 += 32; gA2 += 32; gB1 += 32; gB2 += 32;
      asm volatile("s_waitcnt vmcnt(4)" ::: "memory");
    } else {
      asm volatile("s_waitcnt vmcnt(0)" ::: "memory");
    }
    __builtin_amdgcn_s_barrier();
    short8 af[4], bf[4];
#pragma unroll
    for (int mi = 0; mi < 4; ++mi) af[mi] = *(const short8*)&Alds[cur][aoff[mi]];
#pragma unroll
    for (int ni = 0; ni < 4; ++ni) bf[ni] = *(const short8*)&Blds[cur][boff[ni]];
#pragma unroll
    for (int mi = 0; mi < 4; ++mi)
#pragma unroll
      for (int ni = 0; ni < 4; ++ni)
        acc[mi][ni] = __builtin_amdgcn_mfma_f32_16x16x32_bf16(af[mi], bf[ni], acc[mi][ni], 0, 0, 0);
    __builtin_amdgcn_s_barrier();
    cur ^= 1;
  }

  if (region == 2) {
    // V: transposed bf16 out -> Vtp[(b*1024 + n)*2048 + s]
#pragma unroll
    for (int mi = 0; mi < 4; ++mi) {
      int mb = m0 + wm + mi * 16 + g * 4;
      int bb = mb >> 11, s = mb & 2047;
#pragma unroll
      for (int ni = 0; ni < 4; ++ni) {
        int n = n0 + wn + ni * 16 + li;
        us4 pk = { f2bf(acc[mi][ni][0]), f2bf(acc[mi][ni][1]),
                   f2bf(acc[mi][ni][2]), f2bf(acc[mi][ni][3]) };
        *(us4*)&Vtp[(size_t)(bb * 1024 + n) * 2048 + s] = pk;
      }
    }
  } else {
    unsigned short* C = (region == 0) ? Qp : Kp;
    const float sc = (region == 0) ? qscale : 1.0f;
#pragma unroll
    for (int mi = 0; mi < 4; ++mi) {
      int mb = m0 + wm + mi * 16 + g * 4;
#pragma unroll
      for (int ni = 0; ni < 4; ++ni) {
        int n = n0 + wn + ni * 16 + li;
#pragma unroll
        for (int r = 0; r < 4; ++r)
          C[(size_t)(mb + r) * 1024 + n] = f2bf(acc[mi][ni][r] * sc);
      }
    }
  }
}

// ------------------------------------------------------- output projection GEMM
// Linear grid of 512. XCD-affine: xcd owns m-tiles [8*xcd, 8*xcd+8) for all n;
// per-XCD working set = att 2 MB + Wo 2 MB = one L2. 2-phase pipeline.
__global__ __launch_bounds__(256) void gemm_out(const unsigned short* __restrict__ A,
                                                const unsigned short* __restrict__ W,
                                                float* __restrict__ C) {
  __shared__ unsigned short Alds[2][4096];
  __shared__ unsigned short Blds[2][4096];
  const int tid  = threadIdx.x;
  const int lane = tid & 63;
  const int w    = tid >> 6;
  const int g    = lane >> 4;
  const int li   = lane & 15;

  const int l = blockIdx.x;
  const int xcd = l & 7, j = l >> 3;        // j in [0,64)
  const int mstep = j & 7, nt = j >> 3;     // nt in [0,8)
  const int m0 = (xcd * 8 + mstep) * 128;
  const int n0 = nt * 128;
  const int wm = (w >> 1) * 64;
  const int wn = (w & 1) * 64;

  int aoff[4], boff[4];
#pragma unroll
  for (int mi = 0; mi < 4; ++mi) {
    int row = wm + mi * 16 + li;
    aoff[mi] = row * 32 + (g ^ ((row >> 1) & 3)) * 8;
  }
#pragma unroll
  for (int ni = 0; ni < 4; ++ni) {
    int col = wn + ni * 16 + li;
    boff[ni] = col * 32 + (g ^ ((col >> 1) & 3)) * 8;
  }

  const int s1 = tid, s2 = 256 + tid;
  const int r1 = s1 >> 2, gc1 = (s1 & 3) ^ ((r1 >> 1) & 3);
  const int r2 = s2 >> 2, gc2 = (s2 & 3) ^ ((r2 >> 1) & 3);
  const unsigned short* gA1 = A + (size_t)(m0 + r1) * 1024 + gc1 * 8;
  const unsigned short* gA2 = A + (size_t)(m0 + r2) * 1024 + gc2 * 8;
  const unsigned short* gB1 = W + (size_t)(n0 + r1) * 1024 + gc1 * 8;
  const unsigned short* gB2 = W + (size_t)(n0 + r2) * 1024 + gc2 * 8;

  f32x4 acc[4][4] = {};

  g2l16(gA1, &Alds[0][w * 512]); g2l16(gA2, &Alds[0][2048 + w * 512]);
  g2l16(gB1, &Blds[0][w * 512]); g2l16(gB2, &Blds[0][2048 + w * 512]);
  gA1 += 32; gA2 += 32; gB1 += 32; gB2 += 32;

  int cur = 0;
#pragma unroll 1
  for (int kt = 0; kt < 32; ++kt) {
    if (kt < 31) {
      g2l16(gA1, &Alds[cur ^ 1][w * 512]); g2l16(gA2, &Alds[cur ^ 1][2048 + w * 512]);
      g2l16(gB1, &Blds[cur ^ 1][w * 512]); g2l16(gB2, &Blds[cur ^ 1][2048 + w * 512]);
      gA1 += 32; gA2 += 32; gB1 += 32; gB2 += 32;
      asm volatile("s_waitcnt vmcnt(4)" ::: "memory");
    } else {
      asm volatile("s_waitcnt vmcnt(0)" ::: "memory");
    }
    __builtin_amdgcn_s_barrier();
    short8 af[4], bf[4];
#pragma unroll
    for (int mi = 0; mi < 4; ++mi) af[mi] = *(const short8*)&Alds[cur][aoff[mi]];
#pragma unroll
    for (int ni = 0; ni < 4; ++ni) bf[ni] = *(const short8*)&Blds[cur][boff[ni]];
#pragma unroll
    for (int mi = 0; mi < 4; ++mi)
#pragma unroll
      for (int ni = 0; ni < 4; ++ni)
        acc[mi][ni] = __builtin_amdgcn_mfma_f32_16x16x32_bf16(af[mi], bf[ni], acc[mi][ni], 0, 0, 0);
    __builtin_amdgcn_s_barrier();
    cur ^= 1;
  }

#pragma unroll
  for (int mi = 0; mi < 4; ++mi) {
    int mb = m0 + wm + mi * 16 + g * 4;
#pragma unroll
    for (int ni = 0; ni < 4; ++ni) {
      int n = n0 + wn + ni * 16 + li;
#pragma unroll
      for (int r = 0; r < 4; ++r)
        C[(size_t)(mb + r) * 1024 + n] = acc[mi][ni][r];
    }
  }
}

// ---------------------------------------------------------------- attention v6
// (unchanged from R6: 4 waves, half-tile pair, XCD-affine (b,h) placement)
__global__ __launch_bounds__(256, 4) void attn_kernel(const unsigned short* __restrict__ Qp,
                                                      const unsigned short* __restrict__ Kp,
                                                      const unsigned short* __restrict__ Vt,
                                                      const float* __restrict__ bias,
                                                      const unsigned* __restrict__ flagmask,
                                                      unsigned short* __restrict__ att) {
  __shared__ unsigned short Klds[2][64 * 64];
  __shared__ unsigned short Vlds[2][64 * 64];
  __shared__ unsigned short Plds[4][16 * 64];

  const int tid = threadIdx.x, lane = tid & 63, w = tid >> 6;
  const int g = lane >> 4, li = lane & 15;

  const int rid = blockIdx.x + (blockIdx.y << 4);
  const int xcd = rid & 7, kk = rid >> 3;
  const int bh = (kk & 7) | (xcd << 3);
  const int b = bh >> 4, h = bh & 15;
  const int tA = kk >> 3, tB = 31 - tA;
  const int nA = tA + 1, nB = tB + 1;

  const unsigned smask = flagmask[b];

  const int s1 = tid, s2 = tid + 256;
  const int r1 = s1 >> 3, c1 = (s1 & 7) ^ (r1 & 7);
  const int r2 = s2 >> 3, c2 = (s2 & 7) ^ (r2 & 7);
  const unsigned short* Kb1 = Kp + (size_t)(b * 2048 + r1) * 1024 + h * 64 + c1 * 8;
  const unsigned short* Kb2 = Kp + (size_t)(b * 2048 + r2) * 1024 + h * 64 + c2 * 8;
  const unsigned short* Vb1 = Vt + (size_t)(b * 1024 + h * 64 + r1) * 2048 + c1 * 8;
  const unsigned short* Vb2 = Vt + (size_t)(b * 1024 + h * 64 + r2) * 2048 + c2 * 8;

  int foff[2][4];
#pragma unroll
  for (int ks = 0; ks < 2; ++ks)
#pragma unroll
    for (int i = 0; i < 4; ++i)
      foff[ks][i] = (i * 16 + li) * 64 + (((ks * 4 + g) ^ (li & 7)) * 8);

  unsigned short* Pl = &Plds[w][0];
  const int swr = (li & 7) ^ (li >> 3);
  int poff[2];
#pragma unroll
  for (int ks = 0; ks < 2; ++ks) poff[ks] = li * 64 + ((ks * 4 + g) ^ swr) * 8;

  const float* bbase = bias + b * 2048 + li;

  short8 ones;
#pragma unroll
  for (int j2 = 0; j2 < 8; ++j2) ones[j2] = (short)0x3F80;  // bf16 1.0

  int qw = tA * 64 + w * 16;
  short8 qfr[2];
#pragma unroll
  for (int ks = 0; ks < 2; ++ks)
    qfr[ks] = *(const short8*)&Qp[((size_t)(b * 2048 + qw + li)) * 1024 +
                                  h * 64 + ks * 32 + g * 8];

  f32x4 acco[4] = {};
  f32x4 lacc = {};
  float mrow[4] = {-3.0e38f, -3.0e38f, -3.0e38f, -3.0e38f};
  const f32x4 Z = {0.f, 0.f, 0.f, 0.f};

  auto stage = [&](int kt, int bufn) {
    const size_t ko = (size_t)kt * 65536, vo = (size_t)kt * 64;
    g2l16(Kb1 + ko, &Klds[bufn][w * 512]);
    g2l16(Kb2 + ko, &Klds[bufn][2048 + w * 512]);
    g2l16(Vb1 + vo, &Vlds[bufn][w * 512]);
    g2l16(Vb2 + vo, &Vlds[bufn][2048 + w * 512]);
  };

  auto body = [&](int kt, bool diag, int buf) {
    f32x4 s[4];
#pragma unroll
    for (int ni = 0; ni < 4; ++ni) {
      short8 kf = *(const short8*)&Klds[buf][foff[0][ni]];
      s[ni] = __builtin_amdgcn_mfma_f32_16x16x32_bf16(qfr[0], kf, Z, 0, 0, 0);
    }
#pragma unroll
    for (int ni = 0; ni < 4; ++ni) {
      short8 kf = *(const short8*)&Klds[buf][foff[1][ni]];
      s[ni] = __builtin_amdgcn_mfma_f32_16x16x32_bf16(qfr[1], kf, s[ni], 0, 0, 0);
    }
    if ((smask >> kt) & 1u) {
#pragma unroll
      for (int ni = 0; ni < 4; ++ni) {
        float bv = bbase[kt * 64 + ni * 16];
#pragma unroll
        for (int r = 0; r < 4; ++r) s[ni][r] += bv;
      }
    }
    if (diag) {
      const int q0 = qw + g * 4;
#pragma unroll
      for (int ni = 0; ni < 4; ++ni) {
        const int key = kt * 64 + ni * 16 + li;
#pragma unroll
        for (int r = 0; r < 4; ++r)
          if (key > q0 + r) s[ni][r] = -1.0e9f;
      }
    }
    float tm[4];
#pragma unroll
    for (int r = 0; r < 4; ++r)
      tm[r] = rowmax16(fmaxf(fmaxf(s[0][r], s[1][r]), fmaxf(s[2][r], s[3][r])));
    int need = 0;
#pragma unroll
    for (int r = 0; r < 4; ++r) need |= (tm[r] > mrow[r] + 8.0f) ? 1 : 0;
    if (__any(need)) {
#pragma unroll
      for (int r = 0; r < 4; ++r) {
        const float mn = fmaxf(mrow[r], tm[r]);
        const float al = __builtin_amdgcn_exp2f(mrow[r] - mn);
        mrow[r] = mn;
        lacc[r] *= al;
#pragma unroll
        for (int df = 0; df < 4; ++df) acco[df][r] *= al;
      }
    }
#pragma unroll
    for (int ni = 0; ni < 4; ++ni) {
#pragma unroll
      for (int h2 = 0; h2 < 2; ++h2) {
        float lo = __builtin_amdgcn_exp2f(s[ni][2 * h2]     - mrow[2 * h2]);
        float hi = __builtin_amdgcn_exp2f(s[ni][2 * h2 + 1] - mrow[2 * h2 + 1]);
        unsigned pk = cvt_pk_bf16(lo, hi);
        const int r0 = g * 4 + 2 * h2;
        const int ch = 2 * ni + (li >> 3);
        const int lo7 = li & 7;
        Pl[r0 * 64 + ((ch ^ ((r0 & 7) ^ (g >> 1))) * 8) + lo7] = (unsigned short)pk;
        const int rr = r0 + 1;
        Pl[rr * 64 + ((ch ^ ((rr & 7) ^ (g >> 1))) * 8) + lo7] = (unsigned short)(pk >> 16);
      }
    }
#pragma unroll
    for (int ks = 0; ks < 2; ++ks) {
      const short8 pa = *(const short8*)&Pl[poff[ks]];
      short8 vf[4];
#pragma unroll
      for (int df = 0; df < 4; ++df) vf[df] = *(const short8*)&Vlds[buf][foff[ks][df]];
#pragma unroll
      for (int df = 0; df < 4; ++df)
        acco[df] = __builtin_amdgcn_mfma_f32_16x16x32_bf16(pa, vf[df], acco[df], 0, 0, 0);
      lacc = __builtin_amdgcn_mfma_f32_16x16x32_bf16(pa, ones, lacc, 0, 0, 0);
    }
  };

  auto epilogue = [&]() {
    float inv[4];
#pragma unroll
    for (int r = 0; r < 4; ++r) inv[r] = __builtin_amdgcn_rcpf(lacc[r]);
    const int qb0 = qw + g * 4;
#pragma unroll
    for (int df = 0; df < 4; ++df) {
      const int d = h * 64 + df * 16 + li;
#pragma unroll
      for (int r = 0; r < 4; ++r)
        att[(size_t)(b * 2048 + qb0 + r) * 1024 + d] = f2bf(acco[df][r] * inv[r]);
    }
  };

  stage(0, 0);
  int buf = 0;

#pragma unroll 1
  for (int kt = 0; kt < nA; ++kt) {
    stage((kt + 1 < nA) ? kt + 1 : 0, buf ^ 1);
    asm volatile("s_waitcnt vmcnt(4)" ::: "memory");
    __builtin_amdgcn_s_barrier();
    body(kt, kt == nA - 1, buf);
    __builtin_amdgcn_s_barrier();
    buf ^= 1;
  }

  epilogue();
  qw = tB * 64 + w * 16;
#pragma unroll
  for (int ks = 0; ks < 2; ++ks)
    qfr[ks] = *(const short8*)&Qp[((size_t)(b * 2048 + qw + li)) * 1024 +
                                  h * 64 + ks * 32 + g * 8];
#pragma unroll
  for (int df = 0; df < 4; ++df) acco[df] = Z;
  lacc = Z;
#pragma unroll
  for (int r = 0; r < 4; ++r) mrow[r] = -3.0e38f;

#pragma unroll 1
  for (int kt = 0; kt < nB; ++kt) {
    if (kt + 1 < nB) {
      stage(kt + 1, buf ^ 1);
      asm volatile("s_waitcnt vmcnt(4)" ::: "memory");
    } else {
      asm volatile("s_waitcnt vmcnt(0)" ::: "memory");
    }
    __builtin_amdgcn_s_barrier();
    body(kt, kt == nB - 1, buf);
    __builtin_amdgcn_s_barrier();
    buf ^= 1;
  }

  epilogue();
}

// ---------------------------------------------------------------- launch
extern "C" void kernel_launch(void* const* d_in, const int* in_sizes, int n_in,
                              void* d_out, int out_size, void* d_ws, size_t ws_size,
                              hipStream_t stream) {
  const float* q_raw  = (const float*)d_in[0];
  const float* kv_raw = (const float*)d_in[1];
  const int*   pmask  = (const int*)d_in[2];
  const float* Wq = (const float*)d_in[3];
  const float* Wk = (const float*)d_in[4];
  const float* Wv = (const float*)d_in[5];
  const float* Wo = (const float*)d_in[6];
  float* out = (float*)d_out;

  const size_t NEL = 8388608;   // B*S*D
  const size_t WEL = 1048576;   // D*D
  unsigned short* ws   = (unsigned short*)d_ws;
  unsigned short* qbf  = ws;              // reused as att after projections
  unsigned short* kvbf = qbf + NEL;
  unsigned short* wbf  = kvbf + NEL;      // Wq,Wk,Wv,Wo bf16 back-to-back
  unsigned short* Qp   = wbf + 4 * WEL;
  unsigned short* Kp   = Qp + NEL;
  unsigned short* Vtp  = Kp + NEL;        // (B,H,DH,S) transposed V
  float*          bias = (float*)(Vtp + NEL);
  unsigned*       flagmask = (unsigned*)(bias + 8192);
  unsigned short* att  = qbf;             // alias (qbf dead after projections)

  const float sc = 0.125f * 1.44269504088896340736f;  // 1/sqrt(DH) * log2(e)

  cvt6<<<dim3(512, 6), 256, 0, stream>>>(q_raw, kv_raw, Wq, Wk, Wv, Wo, qbf, kvbf, wbf);
  bias_kernel<<<4, 1024, 0, stream>>>(pmask, bias, flagmask);
  gemm_proj<<<1536, 256, 0, stream>>>(qbf, kvbf, wbf, Qp, Kp, Vtp, sc);
  attn_kernel<<<dim3(16, 64), 256, 0, stream>>>(Qp, Kp, Vtp, bias, flagmask, att);
  gemm_out<<<512, 256, 0, stream>>>(att, wbf + 3 * WEL, out);
}

// Round 9
// 177.390 us; speedup vs baseline: 1.8571x; 1.0779x over previous
//
#include <hip/hip_runtime.h>
#include <stdint.h>

typedef __attribute__((ext_vector_type(8))) short  short8;   // 8 bf16 = 4 VGPR MFMA frag
typedef __attribute__((ext_vector_type(4))) float  f32x4;    // MFMA accumulator
typedef __attribute__((ext_vector_type(4))) unsigned short us4;
typedef __attribute__((ext_vector_type(4))) unsigned int u32x4;

static __device__ __forceinline__ unsigned short f2bf(float x) {
  unsigned u = __builtin_bit_cast(unsigned, x);
  u += 0x7FFFu + ((u >> 16) & 1u);          // round-to-nearest-even
  return (unsigned short)(u >> 16);
}

static __device__ __forceinline__ unsigned cvt_pk_bf16(float lo, float hi) {
  unsigned r;
  asm("v_cvt_pk_bf16_f32 %0, %1, %2" : "=v"(r) : "v"(lo), "v"(hi));
  return r;
}

// ------------------------------------------------- fp32 -> bf16 (6 regions)
__global__ __launch_bounds__(256) void cvt6(const float* __restrict__ q_raw,
                                            const float* __restrict__ kv_raw,
                                            const float* __restrict__ Wq,
                                            const float* __restrict__ Wk,
                                            const float* __restrict__ Wv,
                                            const float* __restrict__ Wo,
                                            unsigned short* __restrict__ qbf,
                                            unsigned short* __restrict__ kvbf,
                                            unsigned short* __restrict__ wbf) {
  const int y = blockIdx.y;
  const float* in;
  unsigned short* out;
  int n4;
  if (y == 0)      { in = q_raw;  out = qbf;  n4 = 2097152; }
  else if (y == 1) { in = kv_raw; out = kvbf; n4 = 2097152; }
  else {
    in  = (y == 2) ? Wq : (y == 3) ? Wk : (y == 4) ? Wv : Wo;
    out = wbf + (size_t)(y - 2) * 1048576;
    n4 = 262144;
  }
  int i = blockIdx.x * 256 + threadIdx.x;
  const int stride = gridDim.x * 256;
  for (; i < n4; i += stride) {
    f32x4 v = *((const f32x4*)in + i);
    us4 o = { f2bf(v[0]), f2bf(v[1]), f2bf(v[2]), f2bf(v[3]) };
    *((us4*)out + i) = o;
  }
}

// ---------------------- pmask -> f32 bias + per-batch 32-bit dirty-tile mask
__global__ __launch_bounds__(1024) void bias_kernel(const int* __restrict__ pm,
                                                    float* __restrict__ bias,
                                                    unsigned* __restrict__ flagmask) {
  __shared__ unsigned m;
  const int b = blockIdx.x, tid = threadIdx.x;
  if (tid == 0) m = 0;
  __syncthreads();
  const int i0 = b * 2048 + tid;
  const int z0 = pm[i0], z1 = pm[i0 + 1024];
  bias[i0]        = z0 ? 0.f : -1.0e9f;
  bias[i0 + 1024] = z1 ? 0.f : -1.0e9f;
  const int wv = tid >> 6;                  // wave index 0..15 = tile index
  unsigned long long b0 = __ballot(z0 == 0);
  unsigned long long b1 = __ballot(z1 == 0);
  if ((tid & 63) == 0) {
    unsigned bits = (b0 ? (1u << wv) : 0u) | (b1 ? (1u << (wv + 16)) : 0u);
    if (bits) atomicOr(&m, bits);
  }
  __syncthreads();
  if (tid == 0) flagmask[b] = m;
}

// ------------------------------------------------------- async global->LDS 16B
static __device__ __forceinline__ void g2l16(const void* g, void* l) {
  __builtin_amdgcn_global_load_lds(
      (const __attribute__((address_space(1))) void*)g,
      (__attribute__((address_space(3))) void*)l, 16, 0, 0);
}

// ------------------------------------------- fused Q/K/V projection NT GEMM
// Linear grid of 1536. XCD-affine: xcd = l&7 owns m-tiles [8*xcd, 8*xcd+8).
// 2-phase double-buffered staging pipeline (counted vmcnt(4)).
__global__ __launch_bounds__(256) void gemm_proj(const unsigned short* __restrict__ qbf,
                                                 const unsigned short* __restrict__ kvbf,
                                                 const unsigned short* __restrict__ wbf,
                                                 unsigned short* __restrict__ Qp,
                                                 unsigned short* __restrict__ Kp,
                                                 unsigned short* __restrict__ Vtp,
                                                 float qscale) {
  __shared__ unsigned short Alds[2][4096];
  __shared__ unsigned short Blds[2][4096];
  const int tid  = threadIdx.x;
  const int lane = tid & 63;
  const int w    = tid >> 6;
  const int g    = lane >> 4;
  const int li   = lane & 15;

  const int l = blockIdx.x;
  const int xcd = l & 7, j = l >> 3;
  const int mstep = j & 7, rn = j >> 3;     // rn in [0,24)
  const int region = rn >> 3;               // 0=Q, 1=K, 2=V
  const int n0 = (rn & 7) * 128;
  const int m0 = (xcd * 8 + mstep) * 128;
  const int wm = (w >> 1) * 64;
  const int wn = (w & 1) * 64;

  const unsigned short* A = (region == 0) ? qbf : kvbf;
  const unsigned short* W = wbf + (size_t)region * 1048576;

  int aoff[4], boff[4];
#pragma unroll
  for (int mi = 0; mi < 4; ++mi) {
    int row = wm + mi * 16 + li;
    aoff[mi] = row * 32 + (g ^ ((row >> 1) & 3)) * 8;
  }
#pragma unroll
  for (int ni = 0; ni < 4; ++ni) {
    int col = wn + ni * 16 + li;
    boff[ni] = col * 32 + (g ^ ((col >> 1) & 3)) * 8;
  }

  const int s1 = tid, s2 = 256 + tid;
  const int r1 = s1 >> 2, gc1 = (s1 & 3) ^ ((r1 >> 1) & 3);
  const int r2 = s2 >> 2, gc2 = (s2 & 3) ^ ((r2 >> 1) & 3);
  const unsigned short* gA1 = A + (size_t)(m0 + r1) * 1024 + gc1 * 8;
  const unsigned short* gA2 = A + (size_t)(m0 + r2) * 1024 + gc2 * 8;
  const unsigned short* gB1 = W + (size_t)(n0 + r1) * 1024 + gc1 * 8;
  const unsigned short* gB2 = W + (size_t)(n0 + r2) * 1024 + gc2 * 8;

  f32x4 acc[4][4] = {};

  g2l16(gA1, &Alds[0][w * 512]); g2l16(gA2, &Alds[0][2048 + w * 512]);
  g2l16(gB1, &Blds[0][w * 512]); g2l16(gB2, &Blds[0][2048 + w * 512]);
  gA1 += 32; gA2 += 32; gB1 += 32; gB2 += 32;

  int cur = 0;
#pragma unroll 1
  for (int kt = 0; kt < 32; ++kt) {
    if (kt < 31) {
      g2l16(gA1, &Alds[cur ^ 1][w * 512]); g2l16(gA2, &Alds[cur ^ 1][2048 + w * 512]);
      g2l16(gB1, &Blds[cur ^ 1][w * 512]); g2l16(gB2, &Blds[cur ^ 1][2048 + w * 512]);
      gA1 += 32; gA2 += 32; gB1 += 32; gB2 += 32;
      asm volatile("s_waitcnt vmcnt(4)" ::: "memory");
    } else {
      asm volatile("s_waitcnt vmcnt(0)" ::: "memory");
    }
    __builtin_amdgcn_s_barrier();
    short8 af[4], bf[4];
#pragma unroll
    for (int mi = 0; mi < 4; ++mi) af[mi] = *(const short8*)&Alds[cur][aoff[mi]];
#pragma unroll
    for (int ni = 0; ni < 4; ++ni) bf[ni] = *(const short8*)&Blds[cur][boff[ni]];
#pragma unroll
    for (int mi = 0; mi < 4; ++mi)
#pragma unroll
      for (int ni = 0; ni < 4; ++ni)
        acc[mi][ni] = __builtin_amdgcn_mfma_f32_16x16x32_bf16(af[mi], bf[ni], acc[mi][ni], 0, 0, 0);
    __builtin_amdgcn_s_barrier();
    cur ^= 1;
  }

  if (region == 2) {
#pragma unroll
    for (int mi = 0; mi < 4; ++mi) {
      int mb = m0 + wm + mi * 16 + g * 4;
      int bb = mb >> 11, s = mb & 2047;
#pragma unroll
      for (int ni = 0; ni < 4; ++ni) {
        int n = n0 + wn + ni * 16 + li;
        us4 pk = { f2bf(acc[mi][ni][0]), f2bf(acc[mi][ni][1]),
                   f2bf(acc[mi][ni][2]), f2bf(acc[mi][ni][3]) };
        *(us4*)&Vtp[(size_t)(bb * 1024 + n) * 2048 + s] = pk;
      }
    }
  } else {
    unsigned short* C = (region == 0) ? Qp : Kp;
    const float sc = (region == 0) ? qscale : 1.0f;
#pragma unroll
    for (int mi = 0; mi < 4; ++mi) {
      int mb = m0 + wm + mi * 16 + g * 4;
#pragma unroll
      for (int ni = 0; ni < 4; ++ni) {
        int n = n0 + wn + ni * 16 + li;
#pragma unroll
        for (int r = 0; r < 4; ++r)
          C[(size_t)(mb + r) * 1024 + n] = f2bf(acc[mi][ni][r] * sc);
      }
    }
  }
}

// ------------------------------------------------------- output projection GEMM
__global__ __launch_bounds__(256) void gemm_out(const unsigned short* __restrict__ A,
                                                const unsigned short* __restrict__ W,
                                                float* __restrict__ C) {
  __shared__ unsigned short Alds[2][4096];
  __shared__ unsigned short Blds[2][4096];
  const int tid  = threadIdx.x;
  const int lane = tid & 63;
  const int w    = tid >> 6;
  const int g    = lane >> 4;
  const int li   = lane & 15;

  const int l = blockIdx.x;
  const int xcd = l & 7, j = l >> 3;
  const int mstep = j & 7, nt = j >> 3;
  const int m0 = (xcd * 8 + mstep) * 128;
  const int n0 = nt * 128;
  const int wm = (w >> 1) * 64;
  const int wn = (w & 1) * 64;

  int aoff[4], boff[4];
#pragma unroll
  for (int mi = 0; mi < 4; ++mi) {
    int row = wm + mi * 16 + li;
    aoff[mi] = row * 32 + (g ^ ((row >> 1) & 3)) * 8;
  }
#pragma unroll
  for (int ni = 0; ni < 4; ++ni) {
    int col = wn + ni * 16 + li;
    boff[ni] = col * 32 + (g ^ ((col >> 1) & 3)) * 8;
  }

  const int s1 = tid, s2 = 256 + tid;
  const int r1 = s1 >> 2, gc1 = (s1 & 3) ^ ((r1 >> 1) & 3);
  const int r2 = s2 >> 2, gc2 = (s2 & 3) ^ ((r2 >> 1) & 3);
  const unsigned short* gA1 = A + (size_t)(m0 + r1) * 1024 + gc1 * 8;
  const unsigned short* gA2 = A + (size_t)(m0 + r2) * 1024 + gc2 * 8;
  const unsigned short* gB1 = W + (size_t)(n0 + r1) * 1024 + gc1 * 8;
  const unsigned short* gB2 = W + (size_t)(n0 + r2) * 1024 + gc2 * 8;

  f32x4 acc[4][4] = {};

  g2l16(gA1, &Alds[0][w * 512]); g2l16(gA2, &Alds[0][2048 + w * 512]);
  g2l16(gB1, &Blds[0][w * 512]); g2l16(gB2, &Blds[0][2048 + w * 512]);
  gA1 += 32; gA2 += 32; gB1 += 32; gB2 += 32;

  int cur = 0;
#pragma unroll 1
  for (int kt = 0; kt < 32; ++kt) {
    if (kt < 31) {
      g2l16(gA1, &Alds[cur ^ 1][w * 512]); g2l16(gA2, &Alds[cur ^ 1][2048 + w * 512]);
      g2l16(gB1, &Blds[cur ^ 1][w * 512]); g2l16(gB2, &Blds[cur ^ 1][2048 + w * 512]);
      gA1 += 32; gA2 += 32; gB1 += 32; gB2 += 32;
      asm volatile("s_waitcnt vmcnt(4)" ::: "memory");
    } else {
      asm volatile("s_waitcnt vmcnt(0)" ::: "memory");
    }
    __builtin_amdgcn_s_barrier();
    short8 af[4], bf[4];
#pragma unroll
    for (int mi = 0; mi < 4; ++mi) af[mi] = *(const short8*)&Alds[cur][aoff[mi]];
#pragma unroll
    for (int ni = 0; ni < 4; ++ni) bf[ni] = *(const short8*)&Blds[cur][boff[ni]];
#pragma unroll
    for (int mi = 0; mi < 4; ++mi)
#pragma unroll
      for (int ni = 0; ni < 4; ++ni)
        acc[mi][ni] = __builtin_amdgcn_mfma_f32_16x16x32_bf16(af[mi], bf[ni], acc[mi][ni], 0, 0, 0);
    __builtin_amdgcn_s_barrier();
    cur ^= 1;
  }

#pragma unroll
  for (int mi = 0; mi < 4; ++mi) {
    int mb = m0 + wm + mi * 16 + g * 4;
#pragma unroll
    for (int ni = 0; ni < 4; ++ni) {
      int n = n0 + wn + ni * 16 + li;
#pragma unroll
      for (int r = 0; r < 4; ++r)
        C[(size_t)(mb + r) * 1024 + n] = acc[mi][ni][r];
    }
  }
}

// ---------------------------------------------------------------- attention v8
// Swapped QK^T (s = mfma(K, Q)) with PERMUTED K-fragment rows so each lane's
// score output already holds exactly the keys its PV A-slots need:
//   kf[ni] frag-row r~ sources K row key_sel(ni,r~) =
//       (ni>>1)*32 + (r~>>2)*8 + (ni&1)*4 + (r~&3)
//   => lane (g,li): s[ni][r] = S[kt*64+(ni>>1)*32+g*8+(ni&1)*4+r][q=qw+li]
//   => PV A-slot j (key ks*32+g*8+j) = s[2ks+(j>>2)][j&3]  (in-lane, no LDS/
//      bpermute for P). Softmax fully in-register. LDS = 32 KB.
__global__ __launch_bounds__(256, 4) void attn_kernel(const unsigned short* __restrict__ Qp,
                                                      const unsigned short* __restrict__ Kp,
                                                      const unsigned short* __restrict__ Vt,
                                                      const float* __restrict__ bias,
                                                      const unsigned* __restrict__ flagmask,
                                                      unsigned short* __restrict__ att) {
  __shared__ unsigned short Klds[2][64 * 64];   // 16 KB
  __shared__ unsigned short Vlds[2][64 * 64];   // 16 KB

  const int tid = threadIdx.x, lane = tid & 63, w = tid >> 6;
  const int g = lane >> 4, li = lane & 15;

  const int rid = blockIdx.x + (blockIdx.y << 4);
  const int xcd = rid & 7, kk = rid >> 3;
  const int bh = (kk & 7) | (xcd << 3);
  const int b = bh >> 4, h = bh & 15;
  const int tA = kk >> 3, tB = 31 - tA;
  const int nA = tA + 1, nB = tB + 1;

  const unsigned smask = flagmask[b];

  const int s1 = tid, s2 = tid + 256;
  const int r1 = s1 >> 3, c1 = (s1 & 7) ^ (r1 & 7);
  const int r2 = s2 >> 3, c2 = (s2 & 7) ^ (r2 & 7);
  const unsigned short* Kb1 = Kp + (size_t)(b * 2048 + r1) * 1024 + h * 64 + c1 * 8;
  const unsigned short* Kb2 = Kp + (size_t)(b * 2048 + r2) * 1024 + h * 64 + c2 * 8;
  const unsigned short* Vb1 = Vt + (size_t)(b * 1024 + h * 64 + r1) * 2048 + c1 * 8;
  const unsigned short* Vb2 = Vt + (size_t)(b * 1024 + h * 64 + r2) * 2048 + c2 * 8;

  // K-fragment offsets with permuted rows (key_sel); V-fragment standard.
  int foffK[2][4], foffV[2][4];
#pragma unroll
  for (int ks = 0; ks < 2; ++ks)
#pragma unroll
    for (int ni = 0; ni < 4; ++ni) {
      const int krow = (ni >> 1) * 32 + (li >> 2) * 8 + (ni & 1) * 4 + (li & 3);
      foffK[ks][ni] = krow * 64 + (((ks * 4 + g) ^ (krow & 7)) * 8);
      const int vrow = ni * 16 + li;
      foffV[ks][ni] = vrow * 64 + (((ks * 4 + g) ^ (vrow & 7)) * 8);
    }

  const float* bbase = bias + b * 2048 + g * 8;

  short8 ones;
#pragma unroll
  for (int j2 = 0; j2 < 8; ++j2) ones[j2] = (short)0x3F80;  // bf16 1.0

  int qw = tA * 64 + w * 16;
  short8 qfr[2];
#pragma unroll
  for (int ks = 0; ks < 2; ++ks)
    qfr[ks] = *(const short8*)&Qp[((size_t)(b * 2048 + qw + li)) * 1024 +
                                  h * 64 + ks * 32 + g * 8];

  f32x4 acco[4] = {};
  f32x4 lacc = {};
  float m = -3.0e38f;                        // running max for q-row qw+li
  const f32x4 Z = {0.f, 0.f, 0.f, 0.f};

  auto stage = [&](int kt, int bufn) {
    const size_t ko = (size_t)kt * 65536, vo = (size_t)kt * 64;
    g2l16(Kb1 + ko, &Klds[bufn][w * 512]);
    g2l16(Kb2 + ko, &Klds[bufn][2048 + w * 512]);
    g2l16(Vb1 + vo, &Vlds[bufn][w * 512]);
    g2l16(Vb2 + vo, &Vlds[bufn][2048 + w * 512]);
  };

  auto body = [&](int kt, bool diag, int buf) {
    // ---- QK^T swapped + permuted: s[ni][r] = S[key(ni,g,r)][q=qw+li]
    f32x4 s[4];
    __builtin_amdgcn_s_setprio(1);
#pragma unroll
    for (int ni = 0; ni < 4; ++ni) {
      short8 kf = *(const short8*)&Klds[buf][foffK[0][ni]];
      s[ni] = __builtin_amdgcn_mfma_f32_16x16x32_bf16(kf, qfr[0], Z, 0, 0, 0);
    }
#pragma unroll
    for (int ni = 0; ni < 4; ++ni) {
      short8 kf = *(const short8*)&Klds[buf][foffK[1][ni]];
      s[ni] = __builtin_amdgcn_mfma_f32_16x16x32_bf16(kf, qfr[1], s[ni], 0, 0, 0);
    }
    __builtin_amdgcn_s_setprio(0);
    // ---- padding bias: key(ni,g,r) = kt*64 + (ni>>1)*32 + g*8 + (ni&1)*4 + r
    if ((smask >> kt) & 1u) {
#pragma unroll
      for (int ni = 0; ni < 4; ++ni) {
        f32x4 bv = *(const f32x4*)&bbase[kt * 64 + (ni >> 1) * 32 + (ni & 1) * 4];
#pragma unroll
        for (int r = 0; r < 4; ++r) s[ni][r] += bv[r];
      }
    }
    // ---- causal mask (diagonal iteration only): key > q
    if (diag) {
      const int q0 = qw + li;
#pragma unroll
      for (int ni = 0; ni < 4; ++ni) {
        const int kb = kt * 64 + (ni >> 1) * 32 + g * 8 + (ni & 1) * 4;
#pragma unroll
        for (int r = 0; r < 4; ++r)
          if (kb + r > q0) s[ni][r] = -1.0e9f;
      }
    }
    // ---- row max: in-lane over 16 + cross-g (xor 16, 32)
    f32x4 tv;
#pragma unroll
    for (int r = 0; r < 4; ++r)
      tv[r] = fmaxf(fmaxf(s[0][r], s[1][r]), fmaxf(s[2][r], s[3][r]));
    float tm = fmaxf(fmaxf(tv[0], tv[1]), fmaxf(tv[2], tv[3]));
    tm = fmaxf(tm, __shfl_xor(tm, 16));
    tm = fmaxf(tm, __shfl_xor(tm, 32));
    // ---- defer-max rescale (rare)
    if (__any(tm > m + 8.0f)) {
      const float mn = fmaxf(m, tm);
      const float al = __builtin_amdgcn_exp2f(m - mn);
      m = mn;
      // al for PV-output row q = qw+g*4+r lives in lane g*4+r (li = g*4+r)
      float alpv[4];
#pragma unroll
      for (int r = 0; r < 4; ++r)
        alpv[r] = __builtin_bit_cast(float,
            __builtin_amdgcn_ds_bpermute((g * 4 + r) * 4, __builtin_bit_cast(int, al)));
#pragma unroll
      for (int r = 0; r < 4; ++r) {
        lacc[r] *= alpv[r];
#pragma unroll
        for (int df = 0; df < 4; ++df) acco[df][r] *= alpv[r];
      }
    }
    // ---- p = exp2(s - m) -> bf16 pairs; PV A-frags assembled IN-LANE
    unsigned wpk[4][2];
#pragma unroll
    for (int ni = 0; ni < 4; ++ni) {
#pragma unroll
      for (int a = 0; a < 2; ++a) {
        float lo = __builtin_amdgcn_exp2f(s[ni][2 * a]     - m);
        float hi = __builtin_amdgcn_exp2f(s[ni][2 * a + 1] - m);
        wpk[ni][a] = cvt_pk_bf16(lo, hi);
      }
    }
    // ---- PV (+ ones column for row-sum l)
#pragma unroll
    for (int ks = 0; ks < 2; ++ks) {
      u32x4 pw = { wpk[2 * ks][0], wpk[2 * ks][1], wpk[2 * ks + 1][0], wpk[2 * ks + 1][1] };
      const short8 pa = __builtin_bit_cast(short8, pw);
      short8 vf[4];
#pragma unroll
      for (int df = 0; df < 4; ++df) vf[df] = *(const short8*)&Vlds[buf][foffV[ks][df]];
      __builtin_amdgcn_s_setprio(1);
#pragma unroll
      for (int df = 0; df < 4; ++df)
        acco[df] = __builtin_amdgcn_mfma_f32_16x16x32_bf16(pa, vf[df], acco[df], 0, 0, 0);
      lacc = __builtin_amdgcn_mfma_f32_16x16x32_bf16(pa, ones, lacc, 0, 0, 0);
      __builtin_amdgcn_s_setprio(0);
    }
  };

  auto epilogue = [&]() {
    float inv[4];
#pragma unroll
    for (int r = 0; r < 4; ++r) inv[r] = __builtin_amdgcn_rcpf(lacc[r]);
    const int qb0 = qw + g * 4;
#pragma unroll
    for (int df = 0; df < 4; ++df) {
      const int d = h * 64 + df * 16 + li;
#pragma unroll
      for (int r = 0; r < 4; ++r)
        att[(size_t)(b * 2048 + qb0 + r) * 1024 + d] = f2bf(acco[df][r] * inv[r]);
    }
  };

  stage(0, 0);
  int buf = 0;

#pragma unroll 1
  for (int kt = 0; kt < nA; ++kt) {
    stage((kt + 1 < nA) ? kt + 1 : 0, buf ^ 1);
    asm volatile("s_waitcnt vmcnt(4)" ::: "memory");
    __builtin_amdgcn_s_barrier();
    body(kt, kt == nA - 1, buf);
    __builtin_amdgcn_s_barrier();
    buf ^= 1;
  }

  epilogue();
  qw = tB * 64 + w * 16;
#pragma unroll
  for (int ks = 0; ks < 2; ++ks)
    qfr[ks] = *(const short8*)&Qp[((size_t)(b * 2048 + qw + li)) * 1024 +
                                  h * 64 + ks * 32 + g * 8];
#pragma unroll
  for (int df = 0; df < 4; ++df) acco[df] = Z;
  lacc = Z;
  m = -3.0e38f;

#pragma unroll 1
  for (int kt = 0; kt < nB; ++kt) {
    if (kt + 1 < nB) {
      stage(kt + 1, buf ^ 1);
      asm volatile("s_waitcnt vmcnt(4)" ::: "memory");
    } else {
      asm volatile("s_waitcnt vmcnt(0)" ::: "memory");
    }
    __builtin_amdgcn_s_barrier();
    body(kt, kt == nB - 1, buf);
    __builtin_amdgcn_s_barrier();
    buf ^= 1;
  }

  epilogue();
}

// ---------------------------------------------------------------- launch
extern "C" void kernel_launch(void* const* d_in, const int* in_sizes, int n_in,
                              void* d_out, int out_size, void* d_ws, size_t ws_size,
                              hipStream_t stream) {
  const float* q_raw  = (const float*)d_in[0];
  const float* kv_raw = (const float*)d_in[1];
  const int*   pmask  = (const int*)d_in[2];
  const float* Wq = (const float*)d_in[3];
  const float* Wk = (const float*)d_in[4];
  const float* Wv = (const float*)d_in[5];
  const float* Wo = (const float*)d_in[6];
  float* out = (float*)d_out;

  const size_t NEL = 8388608;   // B*S*D
  const size_t WEL = 1048576;   // D*D
  unsigned short* ws   = (unsigned short*)d_ws;
  unsigned short* qbf  = ws;              // reused as att after projections
  unsigned short* kvbf = qbf + NEL;
  unsigned short* wbf  = kvbf + NEL;      // Wq,Wk,Wv,Wo bf16 back-to-back
  unsigned short* Qp   = wbf + 4 * WEL;
  unsigned short* Kp   = Qp + NEL;
  unsigned short* Vtp  = Kp + NEL;        // (B,H,DH,S) transposed V
  float*          bias = (float*)(Vtp + NEL);
  unsigned*       flagmask = (unsigned*)(bias + 8192);
  unsigned short* att  = qbf;             // alias (qbf dead after projections)

  const float sc = 0.125f * 1.44269504088896340736f;  // 1/sqrt(DH) * log2(e)

  cvt6<<<dim3(512, 6), 256, 0, stream>>>(q_raw, kv_raw, Wq, Wk, Wv, Wo, qbf, kvbf, wbf);
  bias_kernel<<<4, 1024, 0, stream>>>(pmask, bias, flagmask);
  gemm_proj<<<1536, 256, 0, stream>>>(qbf, kvbf, wbf, Qp, Kp, Vtp, sc);
  attn_kernel<<<dim3(16, 64), 256, 0, stream>>>(Qp, Kp, Vtp, bias, flagmask, att);
  gemm_out<<<512, 256, 0, stream>>>(att, wbf + 3 * WEL, out);
}